// Round 1
// baseline (1402.472 us; speedup 1.0000x reference)
//
#include <hip/hip_runtime.h>
#include <hip/hip_bf16.h>

#define B_ 8
#define L_ 2048
#define C_ 512
#define DK_ 64
#define M_ 8
#define R_ 64
#define H_ 1024
#define N_ (B_*L_)
#define NEG_ (-32767.0f)
#define NSEG 32
#define SEGLEN 64

__device__ __forceinline__ float siluf_(float x) { return x / (1.0f + expf(-x)); }

// ---------------- segmented cumsum (running mean) ----------------
// vc[b,l,c] = (1/(l+1)) * sum_{i<=l} qx[b,i,c]
__global__ __launch_bounds__(512) void seg_sum_kernel(const float* __restrict__ qx,
                                                      float* __restrict__ segsum) {
    const int seg = blockIdx.x, b = blockIdx.y, c = threadIdx.x;
    const float* p = qx + ((size_t)b * L_ + (size_t)seg * SEGLEN) * C_ + c;
    float s = 0.f;
    #pragma unroll 8
    for (int i = 0; i < SEGLEN; ++i) s += p[(size_t)i * C_];
    segsum[((size_t)b * NSEG + seg) * C_ + c] = s;
}

__global__ __launch_bounds__(512) void seg_scan_kernel(const float* __restrict__ qx,
                                                       const float* __restrict__ segsum,
                                                       float* __restrict__ vc) {
    const int seg = blockIdx.x, b = blockIdx.y, c = threadIdx.x;
    float off = 0.f;
    for (int s = 0; s < seg; ++s) off += segsum[((size_t)b * NSEG + s) * C_ + c];
    const float* p = qx + ((size_t)b * L_ + (size_t)seg * SEGLEN) * C_ + c;
    float* o = vc + ((size_t)b * L_ + (size_t)seg * SEGLEN) * C_ + c;
    float run = off;
    for (int i = 0; i < SEGLEN; ++i) {
        run += p[(size_t)i * C_];
        const int l = seg * SEGLEN + i;
        o[(size_t)i * C_] = run / (float)(l + 1);
    }
}

// ---------------- generic fp32 tiled GEMM ----------------
// C[M,N] = act(A[M,K] @ W[K,N] + bias). BM=128 fixed, BN in {128,64}. 256 threads.
// ACT: 0 = none, 1 = silu
template<int BN, int ACT, bool BIAS>
__global__ __launch_bounds__(256) void gemm_f32(const float* __restrict__ A,
                                                const float* __restrict__ W,
                                                const float* __restrict__ bias,
                                                float* __restrict__ Cmat,
                                                int Mrows, int K, int N) {
    constexpr int BM = 128, KT = 16;
    constexpr int TN = BN / 16;
    __shared__ float As[KT][BM + 4];
    __shared__ float Bs[KT][BN + 4];
    const int tid = threadIdx.x;
    const int m0 = blockIdx.x * BM;
    const int n0 = blockIdx.y * BN;
    const int trow = tid >> 4, tcol = tid & 15;
    float acc[8][TN];
    #pragma unroll
    for (int i = 0; i < 8; ++i)
        #pragma unroll
        for (int j = 0; j < TN; ++j) acc[i][j] = 0.f;

    for (int k0 = 0; k0 < K; k0 += KT) {
        // A tile: 128x16 floats, transposed into As[k][m]
        #pragma unroll
        for (int i = 0; i < 2; ++i) {
            const int idx = i * 256 + tid;
            const int row = idx >> 2;
            const int k4 = (idx & 3) << 2;
            const float4 v = *(const float4*)(A + (size_t)(m0 + row) * K + k0 + k4);
            As[k4 + 0][row] = v.x; As[k4 + 1][row] = v.y;
            As[k4 + 2][row] = v.z; As[k4 + 3][row] = v.w;
        }
        // B tile: 16xBN floats, direct layout
        constexpr int BV = (KT * BN) / (4 * 256);
        #pragma unroll
        for (int i = 0; i < BV; ++i) {
            const int idx = i * 256 + tid;
            const int rk = idx / (BN / 4);
            const int n4 = (idx % (BN / 4)) << 2;
            *(float4*)&Bs[rk][n4] = *(const float4*)(W + (size_t)(k0 + rk) * N + n0 + n4);
        }
        __syncthreads();
        #pragma unroll
        for (int k = 0; k < KT; ++k) {
            float a[8], bb[TN];
            *(float4*)&a[0] = *(const float4*)&As[k][trow * 8];
            *(float4*)&a[4] = *(const float4*)&As[k][trow * 8 + 4];
            #pragma unroll
            for (int j4 = 0; j4 < TN; j4 += 4)
                *(float4*)&bb[j4] = *(const float4*)&Bs[k][tcol * TN + j4];
            #pragma unroll
            for (int i = 0; i < 8; ++i)
                #pragma unroll
                for (int j = 0; j < TN; ++j)
                    acc[i][j] = fmaf(a[i], bb[j], acc[i][j]);
        }
        __syncthreads();
    }
    #pragma unroll
    for (int i = 0; i < 8; ++i) {
        const size_t row = (size_t)(m0 + trow * 8 + i);
        #pragma unroll
        for (int j4 = 0; j4 < TN; j4 += 4) {
            const int col = n0 + tcol * TN + j4;
            float4 r;
            r.x = acc[i][j4]; r.y = acc[i][j4 + 1]; r.z = acc[i][j4 + 2]; r.w = acc[i][j4 + 3];
            if constexpr (BIAS) {
                const float4 bv = *(const float4*)(bias + col);
                r.x += bv.x; r.y += bv.y; r.z += bv.z; r.w += bv.w;
            }
            if constexpr (ACT == 1) {
                r.x = siluf_(r.x); r.y = siluf_(r.y); r.z = siluf_(r.z); r.w = siluf_(r.w);
            }
            *(float4*)(Cmat + row * N + col) = r;
        }
    }
}

// ---------------- attention-1: scores1 -> sigmoid -> z pre-WO1 ----------------
// zin[b,l,:] = (l==0) ? 0 : concat_m sigmoid(q[b,l,m,:].k[b,l-1,m,:]/8) * v[b,l-1,m,:]
__global__ __launch_bounds__(512) void attn1_kernel(const float* __restrict__ Q,
                                                    const float* __restrict__ Kb,
                                                    const float* __restrict__ Vb,
                                                    float* __restrict__ zin) {
    const int l = blockIdx.x, b = blockIdx.y;
    const size_t row = ((size_t)b * L_ + l) * 512;
    if (l == 0) { zin[row + threadIdx.x] = 0.f; return; }
    const size_t rowp = row - 512;
    float p = Q[row + threadIdx.x] * Kb[rowp + threadIdx.x];
    #pragma unroll
    for (int o = 32; o; o >>= 1) p += __shfl_xor(p, o);
    const float s = p * 0.125f;                  // /sqrt(64)
    const float sig = 1.0f / (1.0f + expf(-s));
    zin[row + threadIdx.x] = sig * Vb[rowp + threadIdx.x];
}

// ---------------- fused residual + LayerNorm ----------------
// out[row] = LN(X[row] + Y[row]) * g + beta ; one wave per row, 4 rows/block
__global__ __launch_bounds__(256) void ln_kernel(const float* __restrict__ X,
                                                 const float* __restrict__ Y,
                                                 const float* __restrict__ g,
                                                 const float* __restrict__ beta,
                                                 float* __restrict__ out) {
    const int w = threadIdx.x >> 6, lane = threadIdx.x & 63;
    const size_t row = (size_t)blockIdx.x * 4 + w;
    const float4* x4 = (const float4*)(X + row * C_);
    const float4* y4 = (const float4*)(Y + row * C_);
    float v[8];
    const float4 a = x4[lane * 2 + 0], b2 = x4[lane * 2 + 1];
    const float4 c = y4[lane * 2 + 0], d = y4[lane * 2 + 1];
    v[0] = a.x + c.x; v[1] = a.y + c.y; v[2] = a.z + c.z; v[3] = a.w + c.w;
    v[4] = b2.x + d.x; v[5] = b2.y + d.y; v[6] = b2.z + d.z; v[7] = b2.w + d.w;
    float s = 0.f;
    #pragma unroll
    for (int j = 0; j < 8; ++j) s += v[j];
    #pragma unroll
    for (int o = 32; o; o >>= 1) s += __shfl_xor(s, o);
    const float mean = s * (1.0f / 512.0f);
    float q = 0.f;
    #pragma unroll
    for (int j = 0; j < 8; ++j) { const float t = v[j] - mean; q += t * t; }
    #pragma unroll
    for (int o = 32; o; o >>= 1) q += __shfl_xor(q, o);
    const float rstd = rsqrtf(q * (1.0f / 512.0f) + 1e-5f);
    const float4 g0 = ((const float4*)g)[lane * 2], g1 = ((const float4*)g)[lane * 2 + 1];
    const float4 bb0 = ((const float4*)beta)[lane * 2], bb1 = ((const float4*)beta)[lane * 2 + 1];
    float4 o0, o1;
    o0.x = (v[0] - mean) * rstd * g0.x + bb0.x;
    o0.y = (v[1] - mean) * rstd * g0.y + bb0.y;
    o0.z = (v[2] - mean) * rstd * g0.z + bb0.z;
    o0.w = (v[3] - mean) * rstd * g0.w + bb0.w;
    o1.x = (v[4] - mean) * rstd * g1.x + bb1.x;
    o1.y = (v[5] - mean) * rstd * g1.y + bb1.y;
    o1.z = (v[6] - mean) * rstd * g1.z + bb1.z;
    o1.w = (v[7] - mean) * rstd * g1.w + bb1.w;
    ((float4*)(out + row * C_))[lane * 2 + 0] = o0;
    ((float4*)(out + row * C_))[lane * 2 + 1] = o1;
}

// ---------------- masked softmax over L (axis=1) per (b,r) ----------------
__global__ __launch_bounds__(256) void psoftmax_kernel(const float* __restrict__ pscore,
                                                       const int* __restrict__ mask,
                                                       float* __restrict__ pAlpha) {
    const int r = blockIdx.x, b = blockIdx.y, t = threadIdx.x;
    __shared__ float red[256];
    float sv[8];
    float lm = -3.4e38f;
    #pragma unroll
    for (int i = 0; i < 8; ++i) {
        const int l = t + i * 256;
        float x = pscore[((size_t)b * L_ + l) * R_ + r];
        if (mask[(size_t)b * L_ + l] == 0) x = NEG_;
        sv[i] = x; lm = fmaxf(lm, x);
    }
    red[t] = lm; __syncthreads();
    for (int o = 128; o; o >>= 1) { if (t < o) red[t] = fmaxf(red[t], red[t + o]); __syncthreads(); }
    const float mx = red[0]; __syncthreads();
    float ls = 0.f;
    #pragma unroll
    for (int i = 0; i < 8; ++i) { sv[i] = expf(sv[i] - mx); ls += sv[i]; }
    red[t] = ls; __syncthreads();
    for (int o = 128; o; o >>= 1) { if (t < o) red[t] += red[t + o]; __syncthreads(); }
    const float inv = 1.0f / red[0];
    #pragma unroll
    for (int i = 0; i < 8; ++i)
        pAlpha[((size_t)b * L_ + t + i * 256) * R_ + r] = sv[i] * inv;
}

// ---------------- pkvx = pAlpha^T @ vx, K-split partials ----------------
// part[b,ks,r,c] = sum over l-chunk of pAlpha[b,l,r]*vx[b,l,c]
__global__ __launch_bounds__(256) void pkv_partial_kernel(const float* __restrict__ pAlpha,
                                                          const float* __restrict__ vx,
                                                          float* __restrict__ part) {
    const int ct = blockIdx.x;   // c tile (64 cols)
    const int ks = blockIdx.y;   // K chunk (256 l's)
    const int b = blockIdx.z;
    constexpr int KT = 16;
    __shared__ float Pa[KT][64 + 4];
    __shared__ float Vx[KT][64 + 4];
    const int tid = threadIdx.x;
    const int trow = tid >> 4, tcol = tid & 15;
    float acc[4][4];
    #pragma unroll
    for (int i = 0; i < 4; ++i)
        #pragma unroll
        for (int j = 0; j < 4; ++j) acc[i][j] = 0.f;
    const int l0 = ks * 256;
    for (int kk = 0; kk < 256; kk += KT) {
        const int lrow = tid >> 4;
        const int q4 = (tid & 15) << 2;
        const size_t lidx = (size_t)b * L_ + l0 + kk + lrow;
        *(float4*)&Pa[lrow][q4] = *(const float4*)(pAlpha + lidx * R_ + q4);
        *(float4*)&Vx[lrow][q4] = *(const float4*)(vx + lidx * C_ + ct * 64 + q4);
        __syncthreads();
        #pragma unroll
        for (int k = 0; k < KT; ++k) {
            float a[4], v[4];
            *(float4*)&a[0] = *(const float4*)&Pa[k][trow * 4];
            *(float4*)&v[0] = *(const float4*)&Vx[k][tcol * 4];
            #pragma unroll
            for (int i = 0; i < 4; ++i)
                #pragma unroll
                for (int j = 0; j < 4; ++j)
                    acc[i][j] = fmaf(a[i], v[j], acc[i][j]);
        }
        __syncthreads();
    }
    #pragma unroll
    for (int i = 0; i < 4; ++i) {
        const int r = trow * 4 + i;
        float4 vv;
        vv.x = acc[i][0]; vv.y = acc[i][1]; vv.z = acc[i][2]; vv.w = acc[i][3];
        *(float4*)(part + (((size_t)b * 8 + ks) * R_ + r) * C_ + ct * 64 + tcol * 4) = vv;
    }
}

__global__ __launch_bounds__(256) void pkv_reduce_kernel(const float* __restrict__ part,
                                                         float* __restrict__ pkvx) {
    const size_t idx = (size_t)blockIdx.x * 256 + threadIdx.x; // over B*R*C
    const size_t b = idx / ((size_t)R_ * C_);
    const size_t rem = idx % ((size_t)R_ * C_);
    float s = 0.f;
    #pragma unroll
    for (int ks = 0; ks < 8; ++ks) s += part[(b * 8 + ks) * ((size_t)R_ * C_) + rem];
    pkvx[idx] = s;
}

// ---------------- attention-2 fused: scores2 -> softmax -> z2 -> gate*z2 ----------------
// block = (b, 32 tokens). keys/queries/values staged in LDS. h written in-place over gate.
__global__ __launch_bounds__(256) void attn2_kernel(const float* __restrict__ queries,
                                                    const float* __restrict__ keys,
                                                    const float* __restrict__ values,
                                                    float* __restrict__ gateh) {
    const int b = blockIdx.y;
    const int l0 = blockIdx.x * 32;
    const int tid = threadIdx.x;
    __shared__ float alphaS[32][68];
    __shared__ float pool[8448];   // phase1: Ks[64][68]+Qs[32][68]; phase2: Vs[64][132]
    float (*Ks)[68] = (float(*)[68])pool;
    float (*Qs)[68] = (float(*)[68])(pool + 64 * 68);

    #pragma unroll
    for (int i = 0; i < 4; ++i) {
        const int idx = i * 256 + tid;
        const int r = idx >> 4;
        const int c4 = (idx & 15) << 2;
        *(float4*)&Ks[r][c4] = *(const float4*)(keys + ((size_t)b * 64 + r) * 64 + c4);
    }
    #pragma unroll
    for (int i = 0; i < 2; ++i) {
        const int idx = i * 256 + tid;
        const int r = idx >> 4;
        const int c4 = (idx & 15) << 2;
        *(float4*)&Qs[r][c4] = *(const float4*)(queries + ((size_t)b * L_ + l0 + r) * 64 + c4);
    }
    __syncthreads();

    // scores: thread -> token t = tid/8, 8 r's (rg*8+j)
    const int t = tid >> 3, rg = tid & 7;
    float sc[8];
    #pragma unroll
    for (int j = 0; j < 8; ++j) sc[j] = 0.f;
    for (int k4 = 0; k4 < 64; k4 += 4) {
        const float4 q = *(const float4*)&Qs[t][k4];
        #pragma unroll
        for (int j = 0; j < 8; ++j) {
            const float4 kk = *(const float4*)&Ks[rg * 8 + j][k4];
            sc[j] += q.x * kk.x + q.y * kk.y + q.z * kk.z + q.w * kk.w;
        }
    }
    float m8 = -3.4e38f;
    #pragma unroll
    for (int j = 0; j < 8; ++j) { sc[j] *= 0.125f; m8 = fmaxf(m8, sc[j]); }
    #pragma unroll
    for (int o = 1; o < 8; o <<= 1) m8 = fmaxf(m8, __shfl_xor(m8, o));
    float es = 0.f;
    #pragma unroll
    for (int j = 0; j < 8; ++j) { sc[j] = expf(sc[j] - m8); es += sc[j]; }
    #pragma unroll
    for (int o = 1; o < 8; o <<= 1) es += __shfl_xor(es, o);
    const float inv = 1.0f / es;
    #pragma unroll
    for (int j = 0; j < 8; ++j) alphaS[t][rg * 8 + j] = sc[j] * inv;

    // z2 + gate-mult, 128-col chunks, V staged in LDS
    float (*Vs)[132] = (float(*)[132])pool;
    const int trow = tid >> 4, tcol = tid & 15;
    for (int ch = 0; ch < 8; ++ch) {
        const int c0 = ch * 128;
        __syncthreads();   // protect pool before overwrite
        #pragma unroll
        for (int i = 0; i < 8; ++i) {
            const int idx = i * 256 + tid;
            const int r = idx >> 5;
            const int c4 = (idx & 31) << 2;
            *(float4*)&Vs[r][c4] = *(const float4*)(values + ((size_t)b * 64 + r) * H_ + c0 + c4);
        }
        __syncthreads();
        float4 a00 = {0,0,0,0}, a01 = {0,0,0,0}, a10 = {0,0,0,0}, a11 = {0,0,0,0};
        #pragma unroll 4
        for (int k = 0; k < 64; ++k) {
            const float w0 = alphaS[trow][k], w1 = alphaS[trow + 16][k];
            const float4 v0 = *(const float4*)&Vs[k][tcol * 8];
            const float4 v1 = *(const float4*)&Vs[k][tcol * 8 + 4];
            a00.x = fmaf(w0, v0.x, a00.x); a00.y = fmaf(w0, v0.y, a00.y);
            a00.z = fmaf(w0, v0.z, a00.z); a00.w = fmaf(w0, v0.w, a00.w);
            a01.x = fmaf(w0, v1.x, a01.x); a01.y = fmaf(w0, v1.y, a01.y);
            a01.z = fmaf(w0, v1.z, a01.z); a01.w = fmaf(w0, v1.w, a01.w);
            a10.x = fmaf(w1, v0.x, a10.x); a10.y = fmaf(w1, v0.y, a10.y);
            a10.z = fmaf(w1, v0.z, a10.z); a10.w = fmaf(w1, v0.w, a10.w);
            a11.x = fmaf(w1, v1.x, a11.x); a11.y = fmaf(w1, v1.y, a11.y);
            a11.z = fmaf(w1, v1.z, a11.z); a11.w = fmaf(w1, v1.w, a11.w);
        }
        #pragma unroll
        for (int tt = 0; tt < 2; ++tt) {
            const size_t base = ((size_t)b * L_ + l0 + trow + tt * 16) * H_ + c0 + tcol * 8;
            const float4 acc0 = tt ? a10 : a00;
            const float4 acc1 = tt ? a11 : a01;
            const float4 g0 = *(const float4*)(gateh + base);
            const float4 g1 = *(const float4*)(gateh + base + 4);
            float4 o0, o1;
            o0.x = g0.x * acc0.x; o0.y = g0.y * acc0.y; o0.z = g0.z * acc0.z; o0.w = g0.w * acc0.w;
            o1.x = g1.x * acc1.x; o1.y = g1.y * acc1.y; o1.z = g1.z * acc1.z; o1.w = g1.w * acc1.w;
            *(float4*)(gateh + base) = o0;
            *(float4*)(gateh + base + 4) = o1;
        }
    }
}

// ---------------- launch ----------------
extern "C" void kernel_launch(void* const* d_in, const int* in_sizes, int n_in,
                              void* d_out, int out_size, void* d_ws, size_t ws_size,
                              hipStream_t stream) {
    const float* qx   = (const float*)d_in[0];
    const float* vx   = (const float*)d_in[1];
    const int*   maskPAD2 = (const int*)d_in[2];
    const float* WQ1  = (const float*)d_in[3];
    const float* WK1  = (const float*)d_in[4];
    const float* WV1  = (const float*)d_in[5];
    const float* WO1  = (const float*)d_in[6];
    const float* qln_g = (const float*)d_in[7];
    const float* qln_b = (const float*)d_in[8];
    const float* Wp   = (const float*)d_in[9];
    const float* bp   = (const float*)d_in[10];
    const float* Wq2  = (const float*)d_in[11];
    const float* bq2  = (const float*)d_in[12];
    const float* Wk2  = (const float*)d_in[13];
    const float* bk2  = (const float*)d_in[14];
    const float* Wv2  = (const float*)d_in[15];
    const float* bv2  = (const float*)d_in[16];
    const float* Wu   = (const float*)d_in[17];
    const float* bu   = (const float*)d_in[18];
    const float* Wo2  = (const float*)d_in[19];
    const float* bo2  = (const float*)d_in[20];
    const float* ln_g = (const float*)d_in[21];
    const float* ln_b = (const float*)d_in[22];
    float* out = (float*)d_out;
    float* ws = (float*)d_ws;

    const size_t NC = (size_t)N_ * C_;
    float* vcb   = ws;              // vc -> zin -> t2 (aliased across stages)
    float* Qb    = ws + NC;         // Q  -> t1
    float* Kb    = ws + 2 * NC;     // K  -> qx1
    float* Vb    = ws + 3 * NC;     // V
    float* gateh = ws + 4 * NC;     // gate -> h (in-place), 2*NC
    float* S     = ws + 6 * NC;
    float* pscore  = S;
    float* pAlpha  = S + (size_t)N_ * R_;
    float* queries = S + 2 * (size_t)N_ * R_;
    float* keysB   = queries + (size_t)N_ * DK_;
    float* valuesB = keysB + (size_t)B_ * R_ * DK_;
    float* pkvx    = valuesB + (size_t)B_ * R_ * H_;
    float* part    = pkvx + (size_t)B_ * R_ * C_;
    float* segsum  = part + (size_t)B_ * 8 * R_ * C_;

    float* zin = vcb;
    float* t1  = Qb;
    float* qx1 = Kb;
    float* t2  = vcb;

    // 1) running mean vc
    seg_sum_kernel<<<dim3(NSEG, B_), 512, 0, stream>>>(qx, segsum);
    seg_scan_kernel<<<dim3(NSEG, B_), 512, 0, stream>>>(qx, segsum, vcb);
    // 2) Q/K/V projections
    gemm_f32<128, 0, false><<<dim3(N_ / 128, 4), 256, 0, stream>>>(qx,  WQ1, nullptr, Qb, N_, C_, 512);
    gemm_f32<128, 0, false><<<dim3(N_ / 128, 4), 256, 0, stream>>>(vcb, WK1, nullptr, Kb, N_, C_, 512);
    gemm_f32<128, 0, false><<<dim3(N_ / 128, 4), 256, 0, stream>>>(vcb, WV1, nullptr, Vb, N_, C_, 512);
    // 3) scores1 -> sigmoid -> z (pre-WO1), shifted
    attn1_kernel<<<dim3(L_, B_), 512, 0, stream>>>(Qb, Kb, Vb, zin);
    // 4) z @ WO1
    gemm_f32<128, 0, false><<<dim3(N_ / 128, 4), 256, 0, stream>>>(zin, WO1, nullptr, t1, N_, C_, 512);
    // 5) qx1 = LN(qx + t1)
    ln_kernel<<<N_ / 4, 256, 0, stream>>>(qx, t1, qln_g, qln_b, qx1);
    // 6) gate = silu(qx1 @ Wu + bu)
    gemm_f32<128, 1, true><<<dim3(N_ / 128, 8), 256, 0, stream>>>(qx1, Wu, bu, gateh, N_, C_, H_);
    // 7) pseudo-attn: pScore, masked softmax over L, pkvx
    gemm_f32<64, 0, true><<<dim3(N_ / 128, 1), 256, 0, stream>>>(vx, Wp, bp, pscore, N_, C_, R_);
    psoftmax_kernel<<<dim3(R_, B_), 256, 0, stream>>>(pscore, maskPAD2, pAlpha);
    pkv_partial_kernel<<<dim3(8, 8, B_), 256, 0, stream>>>(pAlpha, vx, part);
    pkv_reduce_kernel<<<(B_ * R_ * C_) / 256, 256, 0, stream>>>(part, pkvx);
    // 8) queries/keys/values
    gemm_f32<64, 1, true><<<dim3(N_ / 128, 1), 256, 0, stream>>>(qx1, Wq2, bq2, queries, N_, C_, DK_);
    gemm_f32<64, 1, true><<<dim3((B_ * R_) / 128, 1), 256, 0, stream>>>(pkvx, Wk2, bk2, keysB, B_ * R_, C_, DK_);
    gemm_f32<128, 1, true><<<dim3((B_ * R_) / 128, 8), 256, 0, stream>>>(pkvx, Wv2, bv2, valuesB, B_ * R_, C_, H_);
    // 9) fused scores2/softmax/z2/gate-mult -> h (in-place over gate)
    attn2_kernel<<<dim3(L_ / 32, B_), 256, 0, stream>>>(queries, keysB, valuesB, gateh);
    // 10) t2 = h @ Wo2 + bo2 ; out = LN(qx1 + t2)
    gemm_f32<128, 0, true><<<dim3(N_ / 128, 4), 256, 0, stream>>>(gateh, Wo2, bo2, t2, N_, H_, 512);
    ln_kernel<<<N_ / 4, 256, 0, stream>>>(qx1, t2, ln_g, ln_b, out);
}

// Round 2
// 566.292 us; speedup vs baseline: 2.4766x; 2.4766x over previous
//
#include <hip/hip_runtime.h>
#include <hip/hip_bf16.h>

#define B_ 8
#define L_ 2048
#define C_ 512
#define DK_ 64
#define M_ 8
#define R_ 64
#define H_ 1024
#define N_ (B_*L_)
#define NEG_ (-32767.0f)
#define NSEG 32
#define SEGLEN 64

typedef short bf16x8 __attribute__((ext_vector_type(8)));
typedef float f32x4v __attribute__((ext_vector_type(4)));

__device__ __forceinline__ float siluf_(float x) { return x / (1.0f + expf(-x)); }

__device__ __forceinline__ unsigned short f2bf(float f) {
    __hip_bfloat16 h = __float2bfloat16(f);
    return __builtin_bit_cast(unsigned short, h);
}

// async global->LDS, 16B per lane; LDS dest = wave base + lane*16 (linear)
__device__ __forceinline__ void gload_lds16(const void* g, void* l) {
    __builtin_amdgcn_global_load_lds(
        (const __attribute__((address_space(1))) unsigned int*)(uintptr_t)g,
        (__attribute__((address_space(3))) unsigned int*)(unsigned)(uintptr_t)l,
        16, 0, 0);
}

// ---------------- fp32 -> bf16 elementwise ----------------
__global__ __launch_bounds__(256) void cvt_kernel(const float* __restrict__ x,
                                                  unsigned short* __restrict__ y) {
    const size_t i = ((size_t)blockIdx.x * 256 + threadIdx.x) * 4;
    const float4 v = *(const float4*)(x + i);
    ushort4 o = make_ushort4(f2bf(v.x), f2bf(v.y), f2bf(v.z), f2bf(v.w));
    *(ushort4*)(y + i) = o;
}

// ---------------- weight transpose + convert: W[K][N] f32 -> Wt[N][K] bf16 ----------------
__global__ __launch_bounds__(256) void wtrans_kernel(const float* __restrict__ W,
                                                     unsigned short* __restrict__ Wt,
                                                     int K, int N) {
    __shared__ float t[32][33];
    const int n0 = blockIdx.x * 32, k0 = blockIdx.y * 32;
    const int tx = threadIdx.x, ty = threadIdx.y;
    #pragma unroll
    for (int i = 0; i < 32; i += 8)
        t[ty + i][tx] = W[(size_t)(k0 + ty + i) * N + n0 + tx];
    __syncthreads();
    #pragma unroll
    for (int i = 0; i < 32; i += 8)
        Wt[(size_t)(n0 + ty + i) * K + k0 + tx] = f2bf(t[tx][ty + i]);
}

// ---------------- segmented cumsum (running mean), bf16 out ----------------
__global__ __launch_bounds__(512) void seg_sum_kernel(const float* __restrict__ qx,
                                                      float* __restrict__ segsum) {
    const int seg = blockIdx.x, b = blockIdx.y, c = threadIdx.x;
    const float* p = qx + ((size_t)b * L_ + (size_t)seg * SEGLEN) * C_ + c;
    float s = 0.f;
    #pragma unroll 8
    for (int i = 0; i < SEGLEN; ++i) s += p[(size_t)i * C_];
    segsum[((size_t)b * NSEG + seg) * C_ + c] = s;
}

__global__ __launch_bounds__(512) void seg_scan_kernel(const float* __restrict__ qx,
                                                       const float* __restrict__ segsum,
                                                       unsigned short* __restrict__ vc) {
    const int seg = blockIdx.x, b = blockIdx.y, c = threadIdx.x;
    float off = 0.f;
    for (int s = 0; s < seg; ++s) off += segsum[((size_t)b * NSEG + s) * C_ + c];
    const float* p = qx + ((size_t)b * L_ + (size_t)seg * SEGLEN) * C_ + c;
    unsigned short* o = vc + ((size_t)b * L_ + (size_t)seg * SEGLEN) * C_ + c;
    float run = off;
    for (int i = 0; i < SEGLEN; ++i) {
        run += p[(size_t)i * C_];
        const int l = seg * SEGLEN + i;
        o[(size_t)i * C_] = f2bf(run / (float)(l + 1));
    }
}

// ---------------- bf16 MFMA GEMM (m97 structure: 128xBN tile, BK=64, linear LDS,
// global_load_lds w=16, 2 barriers per K-step, 4 waves, 16x16x32 frags) ----------------
// A[M][K] bf16, Wt[N][K] bf16 (pre-transposed), C fp32 = act(A@W + bias)
template<int BN, int ACT, bool BIAS>
__global__ __launch_bounds__(256) void gemm_bf16(const unsigned short* __restrict__ A,
                                                 const unsigned short* __restrict__ Wt,
                                                 const float* __restrict__ bias,
                                                 float* __restrict__ Cmat,
                                                 int K, int N) {
    constexpr int BK = 64;
    constexpr int WN = BN / 2;      // wave n-extent
    constexpr int TN = WN / 16;     // n frags per wave
    __shared__ unsigned short Alds[128 * BK];
    __shared__ unsigned short Blds[BN * BK];
    const int tid = threadIdx.x;
    const int w = tid >> 6, lane = tid & 63;
    const int wm = w >> 1, wn = w & 1;
    const int m0 = blockIdx.x * 128, n0 = blockIdx.y * BN;

    f32x4v acc[4][TN];
    #pragma unroll
    for (int m = 0; m < 4; ++m)
        #pragma unroll
        for (int n = 0; n < TN; ++n)
            acc[m][n] = f32x4v{0.f, 0.f, 0.f, 0.f};

    const int lrow = lane >> 3;          // row within 8-row chunk
    const int lk = (lane & 7) * 8;       // k element offset within chunk

    for (int k0 = 0; k0 < K; k0 += BK) {
        __syncthreads();
        #pragma unroll
        for (int i = 0; i < 4; ++i) {    // A: 16 x 1KB chunks, 4 per wave
            const int c = w * 4 + i;
            const int row = c * 8 + lrow;
            gload_lds16(A + (size_t)(m0 + row) * K + k0 + lk, (char*)Alds + c * 1024);
        }
        #pragma unroll
        for (int i = 0; i < BN / 32; ++i) { // B: BN/8 chunks, BN/32 per wave
            const int c = w * (BN / 32) + i;
            const int col = c * 8 + lrow;
            gload_lds16(Wt + (size_t)(n0 + col) * K + k0 + lk, (char*)Blds + c * 1024);
        }
        __syncthreads();
        #pragma unroll
        for (int kk = 0; kk < 2; ++kk) {
            const int ko = kk * 64 + (lane >> 4) * 16;   // byte offset within row
            bf16x8 af[4], bfr[TN];
            #pragma unroll
            for (int m = 0; m < 4; ++m)
                af[m] = *(const bf16x8*)((const char*)Alds + (wm * 64 + m * 16 + (lane & 15)) * 128 + ko);
            #pragma unroll
            for (int n = 0; n < TN; ++n)
                bfr[n] = *(const bf16x8*)((const char*)Blds + (wn * WN + n * 16 + (lane & 15)) * 128 + ko);
            #pragma unroll
            for (int m = 0; m < 4; ++m)
                #pragma unroll
                for (int n = 0; n < TN; ++n)
                    acc[m][n] = __builtin_amdgcn_mfma_f32_16x16x32_bf16(af[m], bfr[n], acc[m][n], 0, 0, 0);
        }
    }
    // epilogue: D lane map col=lane&15, row=(lane>>4)*4+r  [m89-verified]
    const int r0 = (lane >> 4) * 4;
    #pragma unroll
    for (int n = 0; n < TN; ++n) {
        const int gc = n0 + wn * WN + n * 16 + (lane & 15);
        float bv = 0.f;
        if constexpr (BIAS) bv = bias[gc];
        #pragma unroll
        for (int m = 0; m < 4; ++m) {
            const int gr = m0 + wm * 64 + m * 16 + r0;
            #pragma unroll
            for (int r = 0; r < 4; ++r) {
                float val = acc[m][n][r] + bv;
                if constexpr (ACT == 1) val = siluf_(val);
                Cmat[(size_t)(gr + r) * N + gc] = val;
            }
        }
    }
}

// ---------------- attention-1: scores1 -> sigmoid -> z (bf16 out, shifted) ----------------
__global__ __launch_bounds__(512) void attn1_kernel(const float* __restrict__ Q,
                                                    const float* __restrict__ Kb,
                                                    const float* __restrict__ Vb,
                                                    unsigned short* __restrict__ zbf) {
    const int l = blockIdx.x, b = blockIdx.y;
    const size_t row = ((size_t)b * L_ + l) * 512;
    if (l == 0) { zbf[row + threadIdx.x] = 0; return; }
    const size_t rowp = row - 512;
    float p = Q[row + threadIdx.x] * Kb[rowp + threadIdx.x];
    #pragma unroll
    for (int o = 32; o; o >>= 1) p += __shfl_xor(p, o);
    const float s = p * 0.125f;
    const float sig = 1.0f / (1.0f + expf(-s));
    zbf[row + threadIdx.x] = f2bf(sig * Vb[rowp + threadIdx.x]);
}

// ---------------- fused residual + LayerNorm (optional bf16 mirror) ----------------
__global__ __launch_bounds__(256) void ln_kernel(const float* __restrict__ X,
                                                 const float* __restrict__ Y,
                                                 const float* __restrict__ g,
                                                 const float* __restrict__ beta,
                                                 float* __restrict__ out,
                                                 unsigned short* __restrict__ outb) {
    const int w = threadIdx.x >> 6, lane = threadIdx.x & 63;
    const size_t row = (size_t)blockIdx.x * 4 + w;
    const float4* x4 = (const float4*)(X + row * C_);
    const float4* y4 = (const float4*)(Y + row * C_);
    float v[8];
    const float4 a = x4[lane * 2 + 0], b2 = x4[lane * 2 + 1];
    const float4 c = y4[lane * 2 + 0], d = y4[lane * 2 + 1];
    v[0] = a.x + c.x; v[1] = a.y + c.y; v[2] = a.z + c.z; v[3] = a.w + c.w;
    v[4] = b2.x + d.x; v[5] = b2.y + d.y; v[6] = b2.z + d.z; v[7] = b2.w + d.w;
    float s = 0.f;
    #pragma unroll
    for (int j = 0; j < 8; ++j) s += v[j];
    #pragma unroll
    for (int o = 32; o; o >>= 1) s += __shfl_xor(s, o);
    const float mean = s * (1.0f / 512.0f);
    float q = 0.f;
    #pragma unroll
    for (int j = 0; j < 8; ++j) { const float t = v[j] - mean; q += t * t; }
    #pragma unroll
    for (int o = 32; o; o >>= 1) q += __shfl_xor(q, o);
    const float rstd = rsqrtf(q * (1.0f / 512.0f) + 1e-5f);
    const float4 g0 = ((const float4*)g)[lane * 2], g1 = ((const float4*)g)[lane * 2 + 1];
    const float4 bb0 = ((const float4*)beta)[lane * 2], bb1 = ((const float4*)beta)[lane * 2 + 1];
    float o8[8];
    o8[0] = (v[0] - mean) * rstd * g0.x + bb0.x;
    o8[1] = (v[1] - mean) * rstd * g0.y + bb0.y;
    o8[2] = (v[2] - mean) * rstd * g0.z + bb0.z;
    o8[3] = (v[3] - mean) * rstd * g0.w + bb0.w;
    o8[4] = (v[4] - mean) * rstd * g1.x + bb1.x;
    o8[5] = (v[5] - mean) * rstd * g1.y + bb1.y;
    o8[6] = (v[6] - mean) * rstd * g1.z + bb1.z;
    o8[7] = (v[7] - mean) * rstd * g1.w + bb1.w;
    float4 o0, o1;
    o0.x = o8[0]; o0.y = o8[1]; o0.z = o8[2]; o0.w = o8[3];
    o1.x = o8[4]; o1.y = o8[5]; o1.z = o8[6]; o1.w = o8[7];
    ((float4*)(out + row * C_))[lane * 2 + 0] = o0;
    ((float4*)(out + row * C_))[lane * 2 + 1] = o1;
    if (outb) {
        bf16x8 pk;
        #pragma unroll
        for (int j = 0; j < 8; ++j) pk[j] = (short)f2bf(o8[j]);
        *(bf16x8*)(outb + row * C_ + lane * 8) = pk;
    }
}

// ---------------- masked softmax over L per (b,r) ----------------
__global__ __launch_bounds__(256) void psoftmax_kernel(const float* __restrict__ pscore,
                                                       const int* __restrict__ mask,
                                                       float* __restrict__ pAlpha) {
    const int r = blockIdx.x, b = blockIdx.y, t = threadIdx.x;
    __shared__ float red[256];
    float sv[8];
    float lm = -3.4e38f;
    #pragma unroll
    for (int i = 0; i < 8; ++i) {
        const int l = t + i * 256;
        float x = pscore[((size_t)b * L_ + l) * R_ + r];
        if (mask[(size_t)b * L_ + l] == 0) x = NEG_;
        sv[i] = x; lm = fmaxf(lm, x);
    }
    red[t] = lm; __syncthreads();
    for (int o = 128; o; o >>= 1) { if (t < o) red[t] = fmaxf(red[t], red[t + o]); __syncthreads(); }
    const float mx = red[0]; __syncthreads();
    float ls = 0.f;
    #pragma unroll
    for (int i = 0; i < 8; ++i) { sv[i] = expf(sv[i] - mx); ls += sv[i]; }
    red[t] = ls; __syncthreads();
    for (int o = 128; o; o >>= 1) { if (t < o) red[t] += red[t + o]; __syncthreads(); }
    const float inv = 1.0f / red[0];
    #pragma unroll
    for (int i = 0; i < 8; ++i)
        pAlpha[((size_t)b * L_ + t + i * 256) * R_ + r] = sv[i] * inv;
}

// ---------------- pkvx = pAlpha^T @ vx, K-split partials ----------------
__global__ __launch_bounds__(256) void pkv_partial_kernel(const float* __restrict__ pAlpha,
                                                          const float* __restrict__ vx,
                                                          float* __restrict__ part) {
    const int ct = blockIdx.x, ks = blockIdx.y, b = blockIdx.z;
    constexpr int KT = 16;
    __shared__ float Pa[KT][64 + 4];
    __shared__ float Vx[KT][64 + 4];
    const int tid = threadIdx.x;
    const int trow = tid >> 4, tcol = tid & 15;
    float acc[4][4];
    #pragma unroll
    for (int i = 0; i < 4; ++i)
        #pragma unroll
        for (int j = 0; j < 4; ++j) acc[i][j] = 0.f;
    const int l0 = ks * 256;
    for (int kk = 0; kk < 256; kk += KT) {
        const int lrow = tid >> 4;
        const int q4 = (tid & 15) << 2;
        const size_t lidx = (size_t)b * L_ + l0 + kk + lrow;
        *(float4*)&Pa[lrow][q4] = *(const float4*)(pAlpha + lidx * R_ + q4);
        *(float4*)&Vx[lrow][q4] = *(const float4*)(vx + lidx * C_ + ct * 64 + q4);
        __syncthreads();
        #pragma unroll
        for (int k = 0; k < KT; ++k) {
            float a[4], v[4];
            *(float4*)&a[0] = *(const float4*)&Pa[k][trow * 4];
            *(float4*)&v[0] = *(const float4*)&Vx[k][tcol * 4];
            #pragma unroll
            for (int i = 0; i < 4; ++i)
                #pragma unroll
                for (int j = 0; j < 4; ++j)
                    acc[i][j] = fmaf(a[i], v[j], acc[i][j]);
        }
        __syncthreads();
    }
    #pragma unroll
    for (int i = 0; i < 4; ++i) {
        const int r = trow * 4 + i;
        float4 vv;
        vv.x = acc[i][0]; vv.y = acc[i][1]; vv.z = acc[i][2]; vv.w = acc[i][3];
        *(float4*)(part + (((size_t)b * 8 + ks) * R_ + r) * C_ + ct * 64 + tcol * 4) = vv;
    }
}

__global__ __launch_bounds__(256) void pkv_reduce_kernel(const float* __restrict__ part,
                                                         unsigned short* __restrict__ pkvx) {
    const size_t idx = (size_t)blockIdx.x * 256 + threadIdx.x;
    const size_t b = idx / ((size_t)R_ * C_);
    const size_t rem = idx % ((size_t)R_ * C_);
    float s = 0.f;
    #pragma unroll
    for (int ks = 0; ks < 8; ++ks) s += part[(b * 8 + ks) * ((size_t)R_ * C_) + rem];
    pkvx[idx] = f2bf(s);
}

// ---------------- attention-2 fused: scores2 -> softmax -> z2 -> gate*z2 (bf16 h out) ----------------
__global__ __launch_bounds__(256) void attn2_kernel(const float* __restrict__ queries,
                                                    const float* __restrict__ keys,
                                                    const float* __restrict__ values,
                                                    const float* __restrict__ gate,
                                                    unsigned short* __restrict__ hb) {
    const int b = blockIdx.y;
    const int l0 = blockIdx.x * 32;
    const int tid = threadIdx.x;
    __shared__ float alphaS[32][68];
    __shared__ float pool[8448];
    float (*Ks)[68] = (float(*)[68])pool;
    float (*Qs)[68] = (float(*)[68])(pool + 64 * 68);

    #pragma unroll
    for (int i = 0; i < 4; ++i) {
        const int idx = i * 256 + tid;
        const int r = idx >> 4;
        const int c4 = (idx & 15) << 2;
        *(float4*)&Ks[r][c4] = *(const float4*)(keys + ((size_t)b * 64 + r) * 64 + c4);
    }
    #pragma unroll
    for (int i = 0; i < 2; ++i) {
        const int idx = i * 256 + tid;
        const int r = idx >> 4;
        const int c4 = (idx & 15) << 2;
        *(float4*)&Qs[r][c4] = *(const float4*)(queries + ((size_t)b * L_ + l0 + r) * 64 + c4);
    }
    __syncthreads();

    const int t = tid >> 3, rg = tid & 7;
    float sc[8];
    #pragma unroll
    for (int j = 0; j < 8; ++j) sc[j] = 0.f;
    for (int k4 = 0; k4 < 64; k4 += 4) {
        const float4 q = *(const float4*)&Qs[t][k4];
        #pragma unroll
        for (int j = 0; j < 8; ++j) {
            const float4 kk = *(const float4*)&Ks[rg * 8 + j][k4];
            sc[j] += q.x * kk.x + q.y * kk.y + q.z * kk.z + q.w * kk.w;
        }
    }
    float m8 = -3.4e38f;
    #pragma unroll
    for (int j = 0; j < 8; ++j) { sc[j] *= 0.125f; m8 = fmaxf(m8, sc[j]); }
    #pragma unroll
    for (int o = 1; o < 8; o <<= 1) m8 = fmaxf(m8, __shfl_xor(m8, o));
    float es = 0.f;
    #pragma unroll
    for (int j = 0; j < 8; ++j) { sc[j] = expf(sc[j] - m8); es += sc[j]; }
    #pragma unroll
    for (int o = 1; o < 8; o <<= 1) es += __shfl_xor(es, o);
    const float inv = 1.0f / es;
    #pragma unroll
    for (int j = 0; j < 8; ++j) alphaS[t][rg * 8 + j] = sc[j] * inv;

    float (*Vs)[132] = (float(*)[132])pool;
    const int trow = tid >> 4, tcol = tid & 15;
    for (int ch = 0; ch < 8; ++ch) {
        const int c0 = ch * 128;
        __syncthreads();
        #pragma unroll
        for (int i = 0; i < 8; ++i) {
            const int idx = i * 256 + tid;
            const int r = idx >> 5;
            const int c4 = (idx & 31) << 2;
            *(float4*)&Vs[r][c4] = *(const float4*)(values + ((size_t)b * 64 + r) * H_ + c0 + c4);
        }
        __syncthreads();
        float4 a00 = {0,0,0,0}, a01 = {0,0,0,0}, a10 = {0,0,0,0}, a11 = {0,0,0,0};
        #pragma unroll 4
        for (int k = 0; k < 64; ++k) {
            const float w0 = alphaS[trow][k], w1 = alphaS[trow + 16][k];
            const float4 v0 = *(const float4*)&Vs[k][tcol * 8];
            const float4 v1 = *(const float4*)&Vs[k][tcol * 8 + 4];
            a00.x = fmaf(w0, v0.x, a00.x); a00.y = fmaf(w0, v0.y, a00.y);
            a00.z = fmaf(w0, v0.z, a00.z); a00.w = fmaf(w0, v0.w, a00.w);
            a01.x = fmaf(w0, v1.x, a01.x); a01.y = fmaf(w0, v1.y, a01.y);
            a01.z = fmaf(w0, v1.z, a01.z); a01.w = fmaf(w0, v1.w, a01.w);
            a10.x = fmaf(w1, v0.x, a10.x); a10.y = fmaf(w1, v0.y, a10.y);
            a10.z = fmaf(w1, v0.z, a10.z); a10.w = fmaf(w1, v0.w, a10.w);
            a11.x = fmaf(w1, v1.x, a11.x); a11.y = fmaf(w1, v1.y, a11.y);
            a11.z = fmaf(w1, v1.z, a11.z); a11.w = fmaf(w1, v1.w, a11.w);
        }
        #pragma unroll
        for (int tt = 0; tt < 2; ++tt) {
            const size_t base = ((size_t)b * L_ + l0 + trow + tt * 16) * H_ + c0 + tcol * 8;
            const float4 acc0 = tt ? a10 : a00;
            const float4 acc1 = tt ? a11 : a01;
            const float4 g0 = *(const float4*)(gate + base);
            const float4 g1 = *(const float4*)(gate + base + 4);
            bf16x8 pk;
            pk[0] = (short)f2bf(g0.x * acc0.x); pk[1] = (short)f2bf(g0.y * acc0.y);
            pk[2] = (short)f2bf(g0.z * acc0.z); pk[3] = (short)f2bf(g0.w * acc0.w);
            pk[4] = (short)f2bf(g1.x * acc1.x); pk[5] = (short)f2bf(g1.y * acc1.y);
            pk[6] = (short)f2bf(g1.z * acc1.z); pk[7] = (short)f2bf(g1.w * acc1.w);
            *(bf16x8*)(hb + base) = pk;
        }
    }
}

// ---------------- launch ----------------
extern "C" void kernel_launch(void* const* d_in, const int* in_sizes, int n_in,
                              void* d_out, int out_size, void* d_ws, size_t ws_size,
                              hipStream_t stream) {
    const float* qx   = (const float*)d_in[0];
    const float* vx   = (const float*)d_in[1];
    const int*   maskPAD2 = (const int*)d_in[2];
    const float* WQ1  = (const float*)d_in[3];
    const float* WK1  = (const float*)d_in[4];
    const float* WV1  = (const float*)d_in[5];
    const float* WO1  = (const float*)d_in[6];
    const float* qln_g = (const float*)d_in[7];
    const float* qln_b = (const float*)d_in[8];
    const float* Wp   = (const float*)d_in[9];
    const float* bp   = (const float*)d_in[10];
    const float* Wq2  = (const float*)d_in[11];
    const float* bq2  = (const float*)d_in[12];
    const float* Wk2  = (const float*)d_in[13];
    const float* bk2  = (const float*)d_in[14];
    const float* Wv2  = (const float*)d_in[15];
    const float* bv2  = (const float*)d_in[16];
    const float* Wu   = (const float*)d_in[17];
    const float* bu   = (const float*)d_in[18];
    const float* Wo2  = (const float*)d_in[19];
    const float* bo2  = (const float*)d_in[20];
    const float* ln_g = (const float*)d_in[21];
    const float* ln_b = (const float*)d_in[22];
    float* out = (float*)d_out;

    // ---- workspace layout (bytes) ----
    char* p = (char*)d_ws;
    const size_t NC4 = (size_t)N_ * C_ * 4;     // 33.55 MB
    const size_t NC2 = (size_t)N_ * C_ * 2;     // 16.78 MB
    float* Qf   = (float*)p;            // later: gate (Q+K slots)
    float* Kf   = (float*)(p + NC4);
    float* Vf   = (float*)(p + 2 * NC4);  // later: qx1 fp32
    p += 3 * NC4;
    float* t1   = (float*)p; p += NC4;    // also t2
    float* pscore  = (float*)p; p += (size_t)N_ * R_ * 4;
    float* pAlpha  = (float*)p; p += (size_t)N_ * R_ * 4;
    float* queries = (float*)p; p += (size_t)N_ * DK_ * 4;
    float* keysB   = (float*)p; p += (size_t)B_ * R_ * DK_ * 4;
    float* valuesB = (float*)p; p += (size_t)B_ * R_ * H_ * 4;
    float* part    = (float*)p; p += (size_t)B_ * 8 * R_ * C_ * 4;
    float* segsum  = (float*)p; p += (size_t)B_ * NSEG * C_ * 4;
    unsigned short* qx_bf = (unsigned short*)p; p += NC2;   // later: qx1_bf
    unsigned short* vc_bf = (unsigned short*)p; p += NC2;   // later: zin_bf
    unsigned short* h_bf  = (unsigned short*)p; p += (size_t)N_ * H_ * 2;  // first half doubles as vx_bf
    unsigned short* pkvx_bf = (unsigned short*)p; p += (size_t)B_ * R_ * C_ * 2;
    unsigned short* wq1t = (unsigned short*)p; p += (size_t)C_ * 512 * 2;
    unsigned short* wk1t = (unsigned short*)p; p += (size_t)C_ * 512 * 2;
    unsigned short* wv1t = (unsigned short*)p; p += (size_t)C_ * 512 * 2;
    unsigned short* wo1t = (unsigned short*)p; p += (size_t)C_ * 512 * 2;
    unsigned short* wpt  = (unsigned short*)p; p += (size_t)C_ * R_ * 2;
    unsigned short* wq2t = (unsigned short*)p; p += (size_t)C_ * DK_ * 2;
    unsigned short* wk2t = (unsigned short*)p; p += (size_t)C_ * DK_ * 2;
    unsigned short* wv2t = (unsigned short*)p; p += (size_t)C_ * H_ * 2;
    unsigned short* wut  = (unsigned short*)p; p += (size_t)C_ * H_ * 2;
    unsigned short* wo2t = (unsigned short*)p; p += (size_t)H_ * C_ * 2;

    unsigned short* vx_bf   = h_bf;     // dead before attn2 writes h_bf
    unsigned short* zin_bf  = vc_bf;    // vc dead after K/V GEMMs
    unsigned short* qx1_bf  = qx_bf;    // qx_bf dead after Q GEMM
    float* gate = Qf;                   // Q,K dead after attn1
    float* qx1f = Vf;                   // V dead after attn1
    float* t2   = t1;

    const int cvtBlocks = (N_ * C_) / (256 * 4);
    // 1) conversions + weight prep
    cvt_kernel<<<cvtBlocks, 256, 0, stream>>>(qx, qx_bf);
    cvt_kernel<<<cvtBlocks, 256, 0, stream>>>(vx, vx_bf);
    dim3 tb(32, 8);
    wtrans_kernel<<<dim3(512/32, 512/32), tb, 0, stream>>>(WQ1, wq1t, 512, 512);
    wtrans_kernel<<<dim3(512/32, 512/32), tb, 0, stream>>>(WK1, wk1t, 512, 512);
    wtrans_kernel<<<dim3(512/32, 512/32), tb, 0, stream>>>(WV1, wv1t, 512, 512);
    wtrans_kernel<<<dim3(512/32, 512/32), tb, 0, stream>>>(WO1, wo1t, 512, 512);
    wtrans_kernel<<<dim3(64/32, 512/32),  tb, 0, stream>>>(Wp,  wpt,  512, 64);
    wtrans_kernel<<<dim3(64/32, 512/32),  tb, 0, stream>>>(Wq2, wq2t, 512, 64);
    wtrans_kernel<<<dim3(64/32, 512/32),  tb, 0, stream>>>(Wk2, wk2t, 512, 64);
    wtrans_kernel<<<dim3(1024/32, 512/32), tb, 0, stream>>>(Wv2, wv2t, 512, 1024);
    wtrans_kernel<<<dim3(1024/32, 512/32), tb, 0, stream>>>(Wu,  wut,  512, 1024);
    wtrans_kernel<<<dim3(512/32, 1024/32), tb, 0, stream>>>(Wo2, wo2t, 1024, 512);
    // 2) running mean (bf16)
    seg_sum_kernel<<<dim3(NSEG, B_), 512, 0, stream>>>(qx, segsum);
    seg_scan_kernel<<<dim3(NSEG, B_), 512, 0, stream>>>(qx, segsum, vc_bf);
    // 3) Q/K/V projections (MFMA)
    gemm_bf16<128, 0, false><<<dim3(N_/128, 4), 256, 0, stream>>>(qx_bf, wq1t, nullptr, Qf, 512, 512);
    gemm_bf16<128, 0, false><<<dim3(N_/128, 4), 256, 0, stream>>>(vc_bf, wk1t, nullptr, Kf, 512, 512);
    gemm_bf16<128, 0, false><<<dim3(N_/128, 4), 256, 0, stream>>>(vc_bf, wv1t, nullptr, Vf, 512, 512);
    // 4) attn1 -> zin (bf16)
    attn1_kernel<<<dim3(L_, B_), 512, 0, stream>>>(Qf, Kf, Vf, zin_bf);
    // 5) WO1
    gemm_bf16<128, 0, false><<<dim3(N_/128, 4), 256, 0, stream>>>(zin_bf, wo1t, nullptr, t1, 512, 512);
    // 6) qx1 = LN(qx + t1), fp32 + bf16
    ln_kernel<<<N_/4, 256, 0, stream>>>(qx, t1, qln_g, qln_b, qx1f, qx1_bf);
    // 7) gate = silu(qx1 @ Wu + bu)
    gemm_bf16<128, 1, true><<<dim3(N_/128, 8), 256, 0, stream>>>(qx1_bf, wut, bu, gate, 512, 1024);
    // 8) pseudo-attn
    gemm_bf16<64, 0, true><<<dim3(N_/128, 1), 256, 0, stream>>>(vx_bf, wpt, bp, pscore, 512, 64);
    psoftmax_kernel<<<dim3(R_, B_), 256, 0, stream>>>(pscore, maskPAD2, pAlpha);
    pkv_partial_kernel<<<dim3(8, 8, B_), 256, 0, stream>>>(pAlpha, vx, part);
    pkv_reduce_kernel<<<(B_ * R_ * C_) / 256, 256, 0, stream>>>(part, pkvx_bf);
    // 9) queries/keys/values
    gemm_bf16<64, 1, true><<<dim3(N_/128, 1), 256, 0, stream>>>(qx1_bf, wq2t, bq2, queries, 512, 64);
    gemm_bf16<64, 1, true><<<dim3((B_*R_)/128, 1), 256, 0, stream>>>(pkvx_bf, wk2t, bk2, keysB, 512, 64);
    gemm_bf16<128, 1, true><<<dim3((B_*R_)/128, 8), 256, 0, stream>>>(pkvx_bf, wv2t, bv2, valuesB, 512, 1024);
    // 10) fused attn2 -> h (bf16)
    attn2_kernel<<<dim3(L_/32, B_), 256, 0, stream>>>(queries, keysB, valuesB, gate, h_bf);
    // 11) t2 = h @ Wo2 + bo2 ; out = LN(qx1 + t2)
    gemm_bf16<128, 0, true><<<dim3(N_/128, 4), 256, 0, stream>>>(h_bf, wo2t, bo2, t2, 1024, 512);
    ln_kernel<<<N_/4, 256, 0, stream>>>(qx1f, t2, ln_g, ln_b, out, nullptr);
}

// Round 4
// 496.752 us; speedup vs baseline: 2.8233x; 1.1400x over previous
//
#include <hip/hip_runtime.h>
#include <hip/hip_bf16.h>

#define B_ 8
#define L_ 2048
#define C_ 512
#define DK_ 64
#define M_ 8
#define R_ 64
#define H_ 1024
#define N_ (B_*L_)
#define NEG_ (-32767.0f)
#define NSEG 32
#define SEGLEN 64

typedef short bf16x8 __attribute__((ext_vector_type(8)));
typedef unsigned short us8 __attribute__((ext_vector_type(8)));
typedef float f32x4v __attribute__((ext_vector_type(4)));

__device__ __forceinline__ float siluf_(float x) { return x / (1.0f + expf(-x)); }

__device__ __forceinline__ unsigned short f2bf(float f) {
    __hip_bfloat16 h = __float2bfloat16(f);
    return __builtin_bit_cast(unsigned short, h);
}
__device__ __forceinline__ float bf2f(unsigned short u) {
    unsigned v = (unsigned)u << 16;
    return __builtin_bit_cast(float, v);
}

// async global->LDS, 16B per lane; LDS dest = wave base + lane*16 (linear)
__device__ __forceinline__ void gload_lds16(const void* g, void* l) {
    __builtin_amdgcn_global_load_lds(
        (const __attribute__((address_space(1))) unsigned int*)(uintptr_t)g,
        (__attribute__((address_space(3))) unsigned int*)(unsigned)(uintptr_t)l,
        16, 0, 0);
}

// ---------------- fp32 -> bf16, batched over z (qx, vx) ----------------
__global__ __launch_bounds__(256) void cvt2_kernel(const float* __restrict__ s0,
                                                   const float* __restrict__ s1,
                                                   unsigned short* __restrict__ d0,
                                                   unsigned short* __restrict__ d1) {
    const float* s = blockIdx.z ? s1 : s0;
    unsigned short* d = blockIdx.z ? d1 : d0;
    const size_t i = ((size_t)blockIdx.x * 256 + threadIdx.x) * 8;
    const float4 v0 = *(const float4*)(s + i);
    const float4 v1 = *(const float4*)(s + i + 4);
    us8 o;
    o[0] = f2bf(v0.x); o[1] = f2bf(v0.y); o[2] = f2bf(v0.z); o[3] = f2bf(v0.w);
    o[4] = f2bf(v1.x); o[5] = f2bf(v1.y); o[6] = f2bf(v1.z); o[7] = f2bf(v1.w);
    *(us8*)(d + i) = o;
}

// ---------------- batched weight transpose+convert: W[K][N] f32 -> Wt[N][K] bf16 ----------------
struct WtDesc { const float* src; unsigned short* dst; int K; int N; };
struct WtArgs { WtDesc d[10]; };

__global__ __launch_bounds__(256) void wtrans_all_kernel(WtArgs a) {
    const WtDesc w = a.d[blockIdx.z];
    const int n0 = blockIdx.x * 32, k0 = blockIdx.y * 32;
    if (n0 >= w.N || k0 >= w.K) return;
    __shared__ float t[32][33];
    const int tx = threadIdx.x, ty = threadIdx.y;
    #pragma unroll
    for (int i = 0; i < 32; i += 8)
        t[ty + i][tx] = w.src[(size_t)(k0 + ty + i) * w.N + n0 + tx];
    __syncthreads();
    #pragma unroll
    for (int i = 0; i < 32; i += 8)
        w.dst[(size_t)(n0 + ty + i) * w.K + k0 + tx] = f2bf(t[tx][ty + i]);
}

// ---------------- segmented cumsum (running mean), bf16 in/out ----------------
__global__ __launch_bounds__(512) void seg_sum_kernel(const unsigned short* __restrict__ qx,
                                                      float* __restrict__ segsum) {
    const int seg = blockIdx.x, b = blockIdx.y, c = threadIdx.x;
    const unsigned short* p = qx + ((size_t)b * L_ + (size_t)seg * SEGLEN) * C_ + c;
    float s = 0.f;
    #pragma unroll 8
    for (int i = 0; i < SEGLEN; ++i) s += bf2f(p[(size_t)i * C_]);
    segsum[((size_t)b * NSEG + seg) * C_ + c] = s;
}

__global__ __launch_bounds__(512) void seg_scan_kernel(const unsigned short* __restrict__ qx,
                                                       const float* __restrict__ segsum,
                                                       unsigned short* __restrict__ vc) {
    const int seg = blockIdx.x, b = blockIdx.y, c = threadIdx.x;
    float off = 0.f;
    for (int s = 0; s < seg; ++s) off += segsum[((size_t)b * NSEG + s) * C_ + c];
    const unsigned short* p = qx + ((size_t)b * L_ + (size_t)seg * SEGLEN) * C_ + c;
    unsigned short* o = vc + ((size_t)b * L_ + (size_t)seg * SEGLEN) * C_ + c;
    float run = off;
    for (int i = 0; i < SEGLEN; ++i) {
        run += bf2f(p[(size_t)i * C_]);
        const int l = seg * SEGLEN + i;
        o[(size_t)i * C_] = f2bf(run / (float)(l + 1));
    }
}

// ---------------- bf16 MFMA GEMM (m97 structure) ----------------
// A[M][K] bf16, Wt[N][K] bf16. OUT: 0 = f32 row-major, 1 = bf16 row-major,
// 2 = bf16 transposed-by-64 (valT[(row/64)*N + col][row%64])
template<int BN, int ACT, bool BIAS, int OUT>
__global__ __launch_bounds__(256) void gemm_bf16(const unsigned short* __restrict__ A,
                                                 const unsigned short* __restrict__ Wt,
                                                 const float* __restrict__ bias,
                                                 void* __restrict__ Cout,
                                                 int K, int N) {
    constexpr int BK = 64;
    constexpr int WN = BN / 2;
    constexpr int TN = WN / 16;
    __shared__ unsigned short Alds[128 * BK];
    __shared__ unsigned short Blds[BN * BK];
    const int tid = threadIdx.x;
    const int w = tid >> 6, lane = tid & 63;
    const int wm = w >> 1, wn = w & 1;
    const int m0 = blockIdx.x * 128, n0 = blockIdx.y * BN;

    f32x4v acc[4][TN];
    #pragma unroll
    for (int m = 0; m < 4; ++m)
        #pragma unroll
        for (int n = 0; n < TN; ++n)
            acc[m][n] = f32x4v{0.f, 0.f, 0.f, 0.f};

    const int lrow = lane >> 3;
    const int lk = (lane & 7) * 8;

    for (int k0 = 0; k0 < K; k0 += BK) {
        __syncthreads();
        #pragma unroll
        for (int i = 0; i < 4; ++i) {
            const int c = w * 4 + i;
            const int row = c * 8 + lrow;
            gload_lds16(A + (size_t)(m0 + row) * K + k0 + lk, (char*)Alds + c * 1024);
        }
        #pragma unroll
        for (int i = 0; i < BN / 32; ++i) {
            const int c = w * (BN / 32) + i;
            const int col = c * 8 + lrow;
            gload_lds16(Wt + (size_t)(n0 + col) * K + k0 + lk, (char*)Blds + c * 1024);
        }
        __syncthreads();
        #pragma unroll
        for (int kk = 0; kk < 2; ++kk) {
            const int ko = kk * 64 + (lane >> 4) * 16;
            bf16x8 af[4], bfr[TN];
            #pragma unroll
            for (int m = 0; m < 4; ++m)
                af[m] = *(const bf16x8*)((const char*)Alds + (wm * 64 + m * 16 + (lane & 15)) * 128 + ko);
            #pragma unroll
            for (int n = 0; n < TN; ++n)
                bfr[n] = *(const bf16x8*)((const char*)Blds + (wn * WN + n * 16 + (lane & 15)) * 128 + ko);
            #pragma unroll
            for (int m = 0; m < 4; ++m)
                #pragma unroll
                for (int n = 0; n < TN; ++n)
                    acc[m][n] = __builtin_amdgcn_mfma_f32_16x16x32_bf16(af[m], bfr[n], acc[m][n], 0, 0, 0);
        }
    }
    const int r0 = (lane >> 4) * 4;
    #pragma unroll
    for (int n = 0; n < TN; ++n) {
        const int gc = n0 + wn * WN + n * 16 + (lane & 15);
        float bv = 0.f;
        if constexpr (BIAS) bv = bias[gc];
        #pragma unroll
        for (int m = 0; m < 4; ++m) {
            const int gr = m0 + wm * 64 + m * 16 + r0;
            float val[4];
            #pragma unroll
            for (int r = 0; r < 4; ++r) {
                val[r] = acc[m][n][r] + bv;
                if constexpr (ACT == 1) val[r] = siluf_(val[r]);
            }
            if constexpr (OUT == 0) {
                #pragma unroll
                for (int r = 0; r < 4; ++r)
                    ((float*)Cout)[(size_t)(gr + r) * N + gc] = val[r];
            } else if constexpr (OUT == 1) {
                #pragma unroll
                for (int r = 0; r < 4; ++r)
                    ((unsigned short*)Cout)[(size_t)(gr + r) * N + gc] = f2bf(val[r]);
            } else {
                ushort4 pk;
                pk.x = f2bf(val[0]); pk.y = f2bf(val[1]);
                pk.z = f2bf(val[2]); pk.w = f2bf(val[3]);
                *(ushort4*)((unsigned short*)Cout + ((size_t)(gr >> 6) * N + gc) * 64 + (gr & 63)) = pk;
            }
        }
    }
}

// ---------------- attention-1: scores1 -> sigmoid -> z (bf16 in/out, shifted) ----------------
__global__ __launch_bounds__(512) void attn1_kernel(const unsigned short* __restrict__ Q,
                                                    const unsigned short* __restrict__ KV,
                                                    unsigned short* __restrict__ zbf) {
    const int l = blockIdx.x, b = blockIdx.y;
    const size_t row = ((size_t)b * L_ + l) * 512;
    if (l == 0) { zbf[row + threadIdx.x] = 0; return; }
    const size_t rowp = ((size_t)b * L_ + l - 1) * 1024;
    const float qv = bf2f(Q[row + threadIdx.x]);
    const float kv = bf2f(KV[rowp + threadIdx.x]);
    float p = qv * kv;
    #pragma unroll
    for (int o = 32; o; o >>= 1) p += __shfl_xor(p, o);
    const float s = p * 0.125f;
    const float sig = 1.0f / (1.0f + expf(-s));
    const float vv = bf2f(KV[rowp + 512 + threadIdx.x]);
    zbf[row + threadIdx.x] = f2bf(sig * vv);
}

// ---------------- fused residual + LayerNorm (optional bf16 mirror) ----------------
__global__ __launch_bounds__(256) void ln_kernel(const float* __restrict__ X,
                                                 const float* __restrict__ Y,
                                                 const float* __restrict__ g,
                                                 const float* __restrict__ beta,
                                                 float* __restrict__ out,
                                                 unsigned short* __restrict__ outb) {
    const int w = threadIdx.x >> 6, lane = threadIdx.x & 63;
    const size_t row = (size_t)blockIdx.x * 4 + w;
    const float4* x4 = (const float4*)(X + row * C_);
    const float4* y4 = (const float4*)(Y + row * C_);
    float v[8];
    const float4 a = x4[lane * 2 + 0], b2 = x4[lane * 2 + 1];
    const float4 c = y4[lane * 2 + 0], d = y4[lane * 2 + 1];
    v[0] = a.x + c.x; v[1] = a.y + c.y; v[2] = a.z + c.z; v[3] = a.w + c.w;
    v[4] = b2.x + d.x; v[5] = b2.y + d.y; v[6] = b2.z + d.z; v[7] = b2.w + d.w;
    float s = 0.f;
    #pragma unroll
    for (int j = 0; j < 8; ++j) s += v[j];
    #pragma unroll
    for (int o = 32; o; o >>= 1) s += __shfl_xor(s, o);
    const float mean = s * (1.0f / 512.0f);
    float q = 0.f;
    #pragma unroll
    for (int j = 0; j < 8; ++j) { const float t = v[j] - mean; q += t * t; }
    #pragma unroll
    for (int o = 32; o; o >>= 1) q += __shfl_xor(q, o);
    const float rstd = rsqrtf(q * (1.0f / 512.0f) + 1e-5f);
    const float4 g0 = ((const float4*)g)[lane * 2], g1 = ((const float4*)g)[lane * 2 + 1];
    const float4 bb0 = ((const float4*)beta)[lane * 2], bb1 = ((const float4*)beta)[lane * 2 + 1];
    float o8[8];
    o8[0] = (v[0] - mean) * rstd * g0.x + bb0.x;
    o8[1] = (v[1] - mean) * rstd * g0.y + bb0.y;
    o8[2] = (v[2] - mean) * rstd * g0.z + bb0.z;
    o8[3] = (v[3] - mean) * rstd * g0.w + bb0.w;
    o8[4] = (v[4] - mean) * rstd * g1.x + bb1.x;
    o8[5] = (v[5] - mean) * rstd * g1.y + bb1.y;
    o8[6] = (v[6] - mean) * rstd * g1.z + bb1.z;
    o8[7] = (v[7] - mean) * rstd * g1.w + bb1.w;
    float4 o0, o1;
    o0.x = o8[0]; o0.y = o8[1]; o0.z = o8[2]; o0.w = o8[3];
    o1.x = o8[4]; o1.y = o8[5]; o1.z = o8[6]; o1.w = o8[7];
    ((float4*)(out + row * C_))[lane * 2 + 0] = o0;
    ((float4*)(out + row * C_))[lane * 2 + 1] = o1;
    if (outb) {
        us8 pk;
        #pragma unroll
        for (int j = 0; j < 8; ++j) pk[j] = f2bf(o8[j]);
        *(us8*)(outb + row * C_ + lane * 8) = pk;
    }
}

// ---------------- masked softmax over L per (b,r) ----------------
__global__ __launch_bounds__(256) void psoftmax_kernel(const float* __restrict__ pscore,
                                                       const int* __restrict__ mask,
                                                       float* __restrict__ pAlpha) {
    const int r = blockIdx.x, b = blockIdx.y, t = threadIdx.x;
    __shared__ float red[256];
    float sv[8];
    float lm = -3.4e38f;
    #pragma unroll
    for (int i = 0; i < 8; ++i) {
        const int l = t + i * 256;
        float x = pscore[((size_t)b * L_ + l) * R_ + r];
        if (mask[(size_t)b * L_ + l] == 0) x = NEG_;
        sv[i] = x; lm = fmaxf(lm, x);
    }
    red[t] = lm; __syncthreads();
    for (int o = 128; o; o >>= 1) { if (t < o) red[t] = fmaxf(red[t], red[t + o]); __syncthreads(); }
    const float mx = red[0]; __syncthreads();
    float ls = 0.f;
    #pragma unroll
    for (int i = 0; i < 8; ++i) { sv[i] = expf(sv[i] - mx); ls += sv[i]; }
    red[t] = ls; __syncthreads();
    for (int o = 128; o; o >>= 1) { if (t < o) red[t] += red[t + o]; __syncthreads(); }
    const float inv = 1.0f / red[0];
    #pragma unroll
    for (int i = 0; i < 8; ++i)
        pAlpha[((size_t)b * L_ + t + i * 256) * R_ + r] = sv[i] * inv;
}

// ---------------- pkvx = pAlpha^T @ vx, K-split partials ----------------
__global__ __launch_bounds__(256) void pkv_partial_kernel(const float* __restrict__ pAlpha,
                                                          const float* __restrict__ vx,
                                                          float* __restrict__ part) {
    const int ct = blockIdx.x, ks = blockIdx.y, b = blockIdx.z;
    constexpr int KT = 16;
    __shared__ float Pa[KT][64 + 4];
    __shared__ float Vx[KT][64 + 4];
    const int tid = threadIdx.x;
    const int trow = tid >> 4, tcol = tid & 15;
    float acc[4][4];
    #pragma unroll
    for (int i = 0; i < 4; ++i)
        #pragma unroll
        for (int j = 0; j < 4; ++j) acc[i][j] = 0.f;
    const int l0 = ks * 256;
    for (int kk = 0; kk < 256; kk += KT) {
        const int lrow = tid >> 4;
        const int q4 = (tid & 15) << 2;
        const size_t lidx = (size_t)b * L_ + l0 + kk + lrow;
        *(float4*)&Pa[lrow][q4] = *(const float4*)(pAlpha + lidx * R_ + q4);
        *(float4*)&Vx[lrow][q4] = *(const float4*)(vx + lidx * C_ + ct * 64 + q4);
        __syncthreads();
        #pragma unroll
        for (int k = 0; k < KT; ++k) {
            float a[4], v[4];
            *(float4*)&a[0] = *(const float4*)&Pa[k][trow * 4];
            *(float4*)&v[0] = *(const float4*)&Vx[k][tcol * 4];
            #pragma unroll
            for (int i = 0; i < 4; ++i)
                #pragma unroll
                for (int j = 0; j < 4; ++j)
                    acc[i][j] = fmaf(a[i], v[j], acc[i][j]);
        }
        __syncthreads();
    }
    #pragma unroll
    for (int i = 0; i < 4; ++i) {
        const int r = trow * 4 + i;
        float4 vv;
        vv.x = acc[i][0]; vv.y = acc[i][1]; vv.z = acc[i][2]; vv.w = acc[i][3];
        *(float4*)(part + (((size_t)b * 8 + ks) * R_ + r) * C_ + ct * 64 + tcol * 4) = vv;
    }
}

__global__ __launch_bounds__(256) void pkv_reduce_kernel(const float* __restrict__ part,
                                                         unsigned short* __restrict__ pkvx) {
    const size_t idx = (size_t)blockIdx.x * 256 + threadIdx.x;
    const size_t b = idx / ((size_t)R_ * C_);
    const size_t rem = idx % ((size_t)R_ * C_);
    float s = 0.f;
    #pragma unroll
    for (int ks = 0; ks < 8; ++ks) s += part[(b * 8 + ks) * ((size_t)R_ * C_) + rem];
    pkvx[idx] = f2bf(s);
}

// ---------------- attention-2 fused, MFMA: scores2 -> softmax -> z2 -> gate*z2 ----------------
// block = (b, 32 tokens), 4 waves. valT[b][h][r] bf16, gate bf16, h out bf16.
__global__ __launch_bounds__(256) void attn2_kernel(const unsigned short* __restrict__ q,
                                                    const unsigned short* __restrict__ k,
                                                    const unsigned short* __restrict__ vT,
                                                    const unsigned short* __restrict__ gate,
                                                    unsigned short* __restrict__ hb) {
    const int b = blockIdx.y, l0 = blockIdx.x * 32;
    const int tid = threadIdx.x, w = tid >> 6, lane = tid & 63;
    __shared__ float sc_s[32][68];
    __shared__ unsigned short al_s[32][72];

    // phase A: scores [32 tok x 64 r]; wave w owns r-frag w (16 r's)
    {
        f32x4v acc[2];
        acc[0] = f32x4v{0.f,0.f,0.f,0.f}; acc[1] = f32x4v{0.f,0.f,0.f,0.f};
        const int r0 = w * 16;
        #pragma unroll
        for (int kk = 0; kk < 2; ++kk) {
            const bf16x8 bfr = *(const bf16x8*)(k + ((size_t)b * 64 + r0 + (lane & 15)) * 64 + kk * 32 + (lane >> 4) * 8);
            #pragma unroll
            for (int m = 0; m < 2; ++m) {
                const bf16x8 af = *(const bf16x8*)(q + ((size_t)b * L_ + l0 + m * 16 + (lane & 15)) * 64 + kk * 32 + (lane >> 4) * 8);
                acc[m] = __builtin_amdgcn_mfma_f32_16x16x32_bf16(af, bfr, acc[m], 0, 0, 0);
            }
        }
        #pragma unroll
        for (int m = 0; m < 2; ++m)
            #pragma unroll
            for (int i = 0; i < 4; ++i)
                sc_s[m * 16 + (lane >> 4) * 4 + i][r0 + (lane & 15)] = acc[m][i];
    }
    __syncthreads();
    // softmax over r: thread -> token t = tid>>3, 8 r's
    {
        const int t = tid >> 3, rg = tid & 7;
        float v[8];
        float mx = -3.4e38f;
        #pragma unroll
        for (int j = 0; j < 8; ++j) { v[j] = sc_s[t][rg * 8 + j] * 0.125f; mx = fmaxf(mx, v[j]); }
        #pragma unroll
        for (int o = 1; o < 8; o <<= 1) mx = fmaxf(mx, __shfl_xor(mx, o));
        float es = 0.f;
        #pragma unroll
        for (int j = 0; j < 8; ++j) { v[j] = expf(v[j] - mx); es += v[j]; }
        #pragma unroll
        for (int o = 1; o < 8; o <<= 1) es += __shfl_xor(es, o);
        const float inv = 1.0f / es;
        #pragma unroll
        for (int j = 0; j < 8; ++j) al_s[t][rg * 8 + j] = f2bf(v[j] * inv);
    }
    __syncthreads();
    // phase B: z2^T = valT @ alpha^T, wave w owns h in [w*256, w*256+256)
    bf16x8 bl[2][2];
    #pragma unroll
    for (int n = 0; n < 2; ++n)
        #pragma unroll
        for (int kk = 0; kk < 2; ++kk)
            bl[n][kk] = *(const bf16x8*)&al_s[n * 16 + (lane & 15)][kk * 32 + (lane >> 4) * 8];
    const int hbase = w * 256;
    #pragma unroll 4
    for (int mi = 0; mi < 16; ++mi) {
        const int h0 = hbase + mi * 16;
        const unsigned short* ap = vT + ((size_t)b * H_ + h0 + (lane & 15)) * 64 + (lane >> 4) * 8;
        const bf16x8 a0 = *(const bf16x8*)(ap);
        const bf16x8 a1 = *(const bf16x8*)(ap + 32);
        f32x4v acc[2];
        acc[0] = f32x4v{0.f,0.f,0.f,0.f}; acc[1] = f32x4v{0.f,0.f,0.f,0.f};
        #pragma unroll
        for (int n = 0; n < 2; ++n) {
            acc[n] = __builtin_amdgcn_mfma_f32_16x16x32_bf16(a0, bl[n][0], acc[n], 0, 0, 0);
            acc[n] = __builtin_amdgcn_mfma_f32_16x16x32_bf16(a1, bl[n][1], acc[n], 0, 0, 0);
        }
        #pragma unroll
        for (int n = 0; n < 2; ++n) {
            const size_t base = ((size_t)b * L_ + l0 + n * 16 + (lane & 15)) * H_ + h0 + (lane >> 4) * 4;
            const ushort4 g = *(const ushort4*)(gate + base);
            ushort4 o;
            o.x = f2bf(bf2f(g.x) * acc[n][0]);
            o.y = f2bf(bf2f(g.y) * acc[n][1]);
            o.z = f2bf(bf2f(g.z) * acc[n][2]);
            o.w = f2bf(bf2f(g.w) * acc[n][3]);
            *(ushort4*)(hb + base) = o;
        }
    }
}

// ---------------- launch ----------------
extern "C" void kernel_launch(void* const* d_in, const int* in_sizes, int n_in,
                              void* d_out, int out_size, void* d_ws, size_t ws_size,
                              hipStream_t stream) {
    const float* qx   = (const float*)d_in[0];
    const float* vx   = (const float*)d_in[1];
    const int*   maskPAD2 = (const int*)d_in[2];
    const float* WQ1  = (const float*)d_in[3];
    const float* WK1  = (const float*)d_in[4];
    const float* WV1  = (const float*)d_in[5];
    const float* WO1  = (const float*)d_in[6];
    const float* qln_g = (const float*)d_in[7];
    const float* qln_b = (const float*)d_in[8];
    const float* Wp   = (const float*)d_in[9];
    const float* bp   = (const float*)d_in[10];
    const float* Wq2  = (const float*)d_in[11];
    const float* bq2  = (const float*)d_in[12];
    const float* Wk2  = (const float*)d_in[13];
    const float* bk2  = (const float*)d_in[14];
    const float* Wv2  = (const float*)d_in[15];
    const float* bv2  = (const float*)d_in[16];
    const float* Wu   = (const float*)d_in[17];
    const float* bu   = (const float*)d_in[18];
    const float* Wo2  = (const float*)d_in[19];
    const float* bo2  = (const float*)d_in[20];
    const float* ln_g = (const float*)d_in[21];
    const float* ln_b = (const float*)d_in[22];
    float* out = (float*)d_out;

    // ---- workspace layout ----
    char* p = (char*)d_ws;
    const size_t NC2 = (size_t)N_ * C_ * 2;          // 16.78 MB
    unsigned short* qx_bf = (unsigned short*)p; p += NC2;         // -> zin_bf -> h_bf[0:half]
    unsigned short* Q_bf  = (unsigned short*)p; p += NC2;         // -> h_bf[half:]
    unsigned short* KV_bf = (unsigned short*)p; p += 2 * NC2;     // -> gate
    unsigned short* vc_bf = (unsigned short*)p; p += NC2;         // -> qx1_bf
    float* t1    = (float*)p; p += (size_t)N_ * C_ * 4;           // -> t2
    float* qx1f  = (float*)p; p += (size_t)N_ * C_ * 4;
    unsigned short* vx_bf = (unsigned short*)p; p += NC2;
    float* pscore  = (float*)p; p += (size_t)N_ * R_ * 4;
    float* pAlpha  = (float*)p; p += (size_t)N_ * R_ * 4;
    unsigned short* queries = (unsigned short*)p; p += (size_t)N_ * DK_ * 2;
    unsigned short* keysB   = (unsigned short*)p; p += (size_t)B_ * R_ * DK_ * 2;
    unsigned short* valT    = (unsigned short*)p; p += (size_t)B_ * H_ * R_ * 2;
    unsigned short* pkvx_bf = (unsigned short*)p; p += (size_t)B_ * R_ * C_ * 2;
    float* part    = (float*)p; p += (size_t)B_ * 8 * R_ * C_ * 4;
    float* segsum  = (float*)p; p += (size_t)B_ * NSEG * C_ * 4;
    unsigned short* wq1t  = (unsigned short*)p; p += (size_t)512 * C_ * 2;
    unsigned short* wkv1t = (unsigned short*)p; p += (size_t)1024 * C_ * 2;
    unsigned short* wo1t  = (unsigned short*)p; p += (size_t)C_ * 512 * 2;
    unsigned short* wpt   = (unsigned short*)p; p += (size_t)R_ * C_ * 2;
    unsigned short* wq2t  = (unsigned short*)p; p += (size_t)DK_ * C_ * 2;
    unsigned short* wk2t  = (unsigned short*)p; p += (size_t)DK_ * C_ * 2;
    unsigned short* wv2t  = (unsigned short*)p; p += (size_t)H_ * C_ * 2;
    unsigned short* wut   = (unsigned short*)p; p += (size_t)H_ * C_ * 2;
    unsigned short* wo2t  = (unsigned short*)p; p += (size_t)C_ * H_ * 2;

    unsigned short* zin_bf = qx_bf;       // qx_bf dead after Q gemm + seg
    unsigned short* h_bf   = qx_bf;       // spans qx_bf + Q_bf (33.5 MB), dead after WO1/attn1
    unsigned short* gate   = KV_bf;       // KV dead after attn1
    unsigned short* qx1_bf = vc_bf;       // vc dead after KV gemm
    float* t2 = t1;

    // 1) conversions + weight prep
    cvt2_kernel<<<dim3((N_ * C_) / (256 * 8), 1, 2), 256, 0, stream>>>(qx, vx, qx_bf, vx_bf);
    WtArgs wa;
    wa.d[0] = {WQ1, wq1t, 512, 512};
    wa.d[1] = {WK1, wkv1t, 512, 512};
    wa.d[2] = {WV1, wkv1t + (size_t)512 * 512, 512, 512};
    wa.d[3] = {WO1, wo1t, 512, 512};
    wa.d[4] = {Wp,  wpt,  512, 64};
    wa.d[5] = {Wq2, wq2t, 512, 64};
    wa.d[6] = {Wk2, wk2t, 512, 64};
    wa.d[7] = {Wv2, wv2t, 512, 1024};
    wa.d[8] = {Wu,  wut,  512, 1024};
    wa.d[9] = {Wo2, wo2t, 1024, 512};
    wtrans_all_kernel<<<dim3(32, 32, 10), dim3(32, 8), 0, stream>>>(wa);
    // 2) running mean (bf16)
    seg_sum_kernel<<<dim3(NSEG, B_), 512, 0, stream>>>(qx_bf, segsum);
    seg_scan_kernel<<<dim3(NSEG, B_), 512, 0, stream>>>(qx_bf, segsum, vc_bf);
    // 3) Q + merged KV projections (MFMA, bf16 out)
    gemm_bf16<128, 0, false, 1><<<dim3(N_/128, 4), 256, 0, stream>>>(qx_bf, wq1t, nullptr, Q_bf, 512, 512);
    gemm_bf16<128, 0, false, 1><<<dim3(N_/128, 8), 256, 0, stream>>>(vc_bf, wkv1t, nullptr, KV_bf, 512, 1024);
    // 4) attn1 -> zin (bf16, overwrites qx_bf)
    attn1_kernel<<<dim3(L_, B_), 512, 0, stream>>>(Q_bf, KV_bf, zin_bf);
    // 5) WO1 -> t1 f32
    gemm_bf16<128, 0, false, 0><<<dim3(N_/128, 4), 256, 0, stream>>>(zin_bf, wo1t, nullptr, t1, 512, 512);
    // 6) qx1 = LN(qx + t1), fp32 + bf16
    ln_kernel<<<N_/4, 256, 0, stream>>>(qx, t1, qln_g, qln_b, qx1f, qx1_bf);
    // 7) gate = silu(qx1 @ Wu + bu), bf16 (overwrites KV_bf)
    gemm_bf16<128, 1, true, 1><<<dim3(N_/128, 8), 256, 0, stream>>>(qx1_bf, wut, bu, gate, 512, 1024);
    // 8) pseudo-attn
    gemm_bf16<64, 0, true, 0><<<dim3(N_/128, 1), 256, 0, stream>>>(vx_bf, wpt, bp, pscore, 512, 64);
    psoftmax_kernel<<<dim3(R_, B_), 256, 0, stream>>>(pscore, maskPAD2, pAlpha);
    pkv_partial_kernel<<<dim3(8, 8, B_), 256, 0, stream>>>(pAlpha, vx, part);
    pkv_reduce_kernel<<<(B_ * R_ * C_) / 256, 256, 0, stream>>>(part, pkvx_bf);
    // 9) queries/keys (bf16), values (bf16 transposed-by-64)
    gemm_bf16<64, 1, true, 1><<<dim3(N_/128, 1), 256, 0, stream>>>(qx1_bf, wq2t, bq2, queries, 512, 64);
    gemm_bf16<64, 1, true, 1><<<dim3((B_*R_)/128, 1), 256, 0, stream>>>(pkvx_bf, wk2t, bk2, keysB, 512, 64);
    gemm_bf16<128, 1, true, 2><<<dim3((B_*R_)/128, 8), 256, 0, stream>>>(pkvx_bf, wv2t, bv2, valT, 512, 1024);
    // 10) fused attn2 (MFMA) -> h bf16 (overwrites qx_bf+Q_bf)
    attn2_kernel<<<dim3(L_/32, B_), 256, 0, stream>>>(queries, keysB, valT, gate, h_bf);
    // 11) t2 = h @ Wo2 + bo2 ; out = LN(qx1 + t2)
    gemm_bf16<128, 0, true, 0><<<dim3(N_/128, 4), 256, 0, stream>>>(h_bf, wo2t, bo2, t2, 1024, 512);
    ln_kernel<<<N_/4, 256, 0, stream>>>(qx1f, t2, ln_g, ln_b, out, nullptr);
}

// Round 6
// 455.198 us; speedup vs baseline: 3.0810x; 1.0913x over previous
//
#include <hip/hip_runtime.h>
#include <hip/hip_bf16.h>

#define B_ 8
#define L_ 2048
#define C_ 512
#define DK_ 64
#define M_ 8
#define R_ 64
#define H_ 1024
#define N_ (B_*L_)
#define NEG_ (-32767.0f)
#define NSEG 32
#define SEGLEN 64

typedef short bf16x8 __attribute__((ext_vector_type(8)));
typedef unsigned short us8 __attribute__((ext_vector_type(8)));
typedef float f32x4v __attribute__((ext_vector_type(4)));

__device__ __forceinline__ float siluf_(float x) { return x / (1.0f + expf(-x)); }

__device__ __forceinline__ unsigned short f2bf(float f) {
    __hip_bfloat16 h = __float2bfloat16(f);
    return __builtin_bit_cast(unsigned short, h);
}
__device__ __forceinline__ float bf2f(unsigned short u) {
    unsigned v = (unsigned)u << 16;
    return __builtin_bit_cast(float, v);
}

// async global->LDS, 16B per lane; LDS dest = wave base + lane*16 (linear)
__device__ __forceinline__ void gload_lds16(const void* g, void* l) {
    __builtin_amdgcn_global_load_lds(
        (const __attribute__((address_space(1))) unsigned int*)(uintptr_t)g,
        (__attribute__((address_space(3))) unsigned int*)(unsigned)(uintptr_t)l,
        16, 0, 0);
}

// ---------------- fp32 -> bf16, batched (qx, vx) ----------------
__global__ __launch_bounds__(256) void cvt2_kernel(const float* __restrict__ s0,
                                                   const float* __restrict__ s1,
                                                   unsigned short* __restrict__ d0,
                                                   unsigned short* __restrict__ d1) {
    const float* s = blockIdx.z ? s1 : s0;
    unsigned short* d = blockIdx.z ? d1 : d0;
    const size_t i = ((size_t)blockIdx.x * 256 + threadIdx.x) * 8;
    const float4 v0 = *(const float4*)(s + i);
    const float4 v1 = *(const float4*)(s + i + 4);
    us8 o;
    o[0] = f2bf(v0.x); o[1] = f2bf(v0.y); o[2] = f2bf(v0.z); o[3] = f2bf(v0.w);
    o[4] = f2bf(v1.x); o[5] = f2bf(v1.y); o[6] = f2bf(v1.z); o[7] = f2bf(v1.w);
    *(us8*)(d + i) = o;
}

// ---------------- batched weight transpose+convert: W[K][N] f32 -> Wt[N][K] bf16 ----------------
struct WtDesc { const float* src; unsigned short* dst; int K; int N; };
struct WtArgs { WtDesc d[10]; };

__global__ __launch_bounds__(256) void wtrans_all_kernel(WtArgs a) {
    const WtDesc w = a.d[blockIdx.z];
    const int n0 = blockIdx.x * 32, k0 = blockIdx.y * 32;
    if (n0 >= w.N || k0 >= w.K) return;
    __shared__ float t[32][33];
    const int tx = threadIdx.x, ty = threadIdx.y;
    #pragma unroll
    for (int i = 0; i < 32; i += 8)
        t[ty + i][tx] = w.src[(size_t)(k0 + ty + i) * w.N + n0 + tx];
    __syncthreads();
    #pragma unroll
    for (int i = 0; i < 32; i += 8)
        w.dst[(size_t)(n0 + ty + i) * w.K + k0 + tx] = f2bf(t[tx][ty + i]);
}

// ---------------- segmented cumsum (running mean), bf16 in/out ----------------
__global__ __launch_bounds__(512) void seg_sum_kernel(const unsigned short* __restrict__ qx,
                                                      float* __restrict__ segsum) {
    const int seg = blockIdx.x, b = blockIdx.y, c = threadIdx.x;
    const unsigned short* p = qx + ((size_t)b * L_ + (size_t)seg * SEGLEN) * C_ + c;
    float s = 0.f;
    #pragma unroll 8
    for (int i = 0; i < SEGLEN; ++i) s += bf2f(p[(size_t)i * C_]);
    segsum[((size_t)b * NSEG + seg) * C_ + c] = s;
}

__global__ __launch_bounds__(512) void seg_scan_kernel(const unsigned short* __restrict__ qx,
                                                       const float* __restrict__ segsum,
                                                       unsigned short* __restrict__ vc) {
    const int seg = blockIdx.x, b = blockIdx.y, c = threadIdx.x;
    float off = 0.f;
    for (int s = 0; s < seg; ++s) off += segsum[((size_t)b * NSEG + s) * C_ + c];
    const unsigned short* p = qx + ((size_t)b * L_ + (size_t)seg * SEGLEN) * C_ + c;
    unsigned short* o = vc + ((size_t)b * L_ + (size_t)seg * SEGLEN) * C_ + c;
    float run = off;
    for (int i = 0; i < SEGLEN; ++i) {
        run += bf2f(p[(size_t)i * C_]);
        const int l = seg * SEGLEN + i;
        o[(size_t)i * C_] = f2bf(run / (float)(l + 1));
    }
}

// ---------------- bf16 MFMA GEMM body (m97 structure + LDS-staged epilogue) ----------------
// A[M][K] bf16, Wt[N][K] bf16. OUT: 0 = f32 row-major (2-pass f32 stage),
// 1 = bf16 row-major (us8 stage), 2 = bf16 transposed-by-64 valT (BN=64 only).
template<int BN, int ACT, bool BIAS, int OUT>
__device__ __forceinline__ void gemm_body(char* smem,
        const unsigned short* __restrict__ A, const unsigned short* __restrict__ Wt,
        const float* __restrict__ bias, void* __restrict__ Cout,
        int K, int N, int m0, int n0, int tid) {
    constexpr int BK = 64;
    constexpr int WN = BN / 2;
    constexpr int TN = WN / 16;
    unsigned short* Alds = (unsigned short*)smem;             // 128*64 us = 16KB
    unsigned short* Blds = (unsigned short*)(smem + 16384);   // BN*64 us
    const int w = tid >> 6, lane = tid & 63;
    const int wm = w >> 1, wn = w & 1;

    f32x4v acc[4][TN];
    #pragma unroll
    for (int m = 0; m < 4; ++m)
        #pragma unroll
        for (int n = 0; n < TN; ++n)
            acc[m][n] = f32x4v{0.f, 0.f, 0.f, 0.f};

    const int lrow = lane >> 3;
    const int lk = (lane & 7) * 8;

    for (int k0 = 0; k0 < K; k0 += BK) {
        __syncthreads();
        #pragma unroll
        for (int i = 0; i < 4; ++i) {
            const int c = w * 4 + i;
            const int row = c * 8 + lrow;
            gload_lds16(A + (size_t)(m0 + row) * K + k0 + lk, (char*)Alds + c * 1024);
        }
        #pragma unroll
        for (int i = 0; i < BN / 32; ++i) {
            const int c = w * (BN / 32) + i;
            const int col = c * 8 + lrow;
            gload_lds16(Wt + (size_t)(n0 + col) * K + k0 + lk, (char*)Blds + c * 1024);
        }
        __syncthreads();
        #pragma unroll
        for (int kk = 0; kk < 2; ++kk) {
            const int ko = kk * 64 + (lane >> 4) * 16;
            bf16x8 af[4], bfr[TN];
            #pragma unroll
            for (int m = 0; m < 4; ++m)
                af[m] = *(const bf16x8*)((const char*)Alds + (wm * 64 + m * 16 + (lane & 15)) * 128 + ko);
            #pragma unroll
            for (int n = 0; n < TN; ++n)
                bfr[n] = *(const bf16x8*)((const char*)Blds + (wn * WN + n * 16 + (lane & 15)) * 128 + ko);
            #pragma unroll
            for (int m = 0; m < 4; ++m)
                #pragma unroll
                for (int n = 0; n < TN; ++n)
                    acc[m][n] = __builtin_amdgcn_mfma_f32_16x16x32_bf16(af[m], bfr[n], acc[m][n], 0, 0, 0);
        }
    }

    // bias per n-frag (col fixed per lane)
    const int r0 = (lane >> 4) * 4;
    float bv[TN];
    #pragma unroll
    for (int n = 0; n < TN; ++n)
        bv[n] = BIAS ? bias[n0 + wn * WN + n * 16 + (lane & 15)] : 0.f;

    if constexpr (OUT == 1) {
        __syncthreads();                                  // all MFMA LDS reads done
        unsigned short* stg = (unsigned short*)smem;      // [128][BN]
        #pragma unroll
        for (int n = 0; n < TN; ++n) {
            const int cl = wn * WN + n * 16 + (lane & 15);
            #pragma unroll
            for (int m = 0; m < 4; ++m)
                #pragma unroll
                for (int r = 0; r < 4; ++r) {
                    float val = acc[m][n][r] + bv[n];
                    if constexpr (ACT == 1) val = siluf_(val);
                    stg[(wm * 64 + m * 16 + r0 + r) * BN + cl] = f2bf(val);
                }
        }
        __syncthreads();
        constexpr int CH = 128 * BN / 8 / 256;
        #pragma unroll
        for (int i = 0; i < CH; ++i) {
            const int idx = i * 256 + tid;
            const int row = (idx * 8) / BN, col = (idx * 8) % BN;
            *(us8*)((unsigned short*)Cout + (size_t)(m0 + row) * N + n0 + col) = *(const us8*)&stg[idx * 8];
        }
    } else if constexpr (OUT == 2) {
        // BN==64 only. stage [2*BN][72] us (pad 8 for alignment+banks)
        __syncthreads();
        unsigned short* stg = (unsigned short*)smem;
        #pragma unroll
        for (int n = 0; n < TN; ++n) {
            const int cl = wn * WN + n * 16 + (lane & 15);
            #pragma unroll
            for (int m = 0; m < 4; ++m)
                #pragma unroll
                for (int r = 0; r < 4; ++r) {
                    float val = acc[m][n][r] + bv[n];
                    if constexpr (ACT == 1) val = siluf_(val);
                    stg[(wm * BN + cl) * 72 + m * 16 + r0 + r] = f2bf(val);
                }
        }
        __syncthreads();
        constexpr int CH = 2 * BN * 64 / 8 / 256;
        #pragma unroll
        for (int i = 0; i < CH; ++i) {
            const int idx = i * 256 + tid;
            const int vrow = idx >> 3, j = (idx & 7) * 8;
            const int h = vrow >= BN ? 1 : 0;
            const int col = vrow & (BN - 1);
            *(us8*)((unsigned short*)Cout + (((size_t)(m0 >> 6) + h) * N + n0 + col) * 64 + j)
                = *(const us8*)&stg[vrow * 72 + j];
        }
    } else {
        // OUT==0: f32 row-major, two 64-row passes through a [64][BN] f32 stage
        float* stgf = (float*)smem;
        #pragma unroll
        for (int pass = 0; pass < 2; ++pass) {
            __syncthreads();
            if (wm == pass) {
                #pragma unroll
                for (int n = 0; n < TN; ++n) {
                    const int cl = wn * WN + n * 16 + (lane & 15);
                    #pragma unroll
                    for (int m = 0; m < 4; ++m)
                        #pragma unroll
                        for (int r = 0; r < 4; ++r) {
                            float val = acc[m][n][r] + bv[n];
                            if constexpr (ACT == 1) val = siluf_(val);
                            stgf[(m * 16 + r0 + r) * BN + cl] = val;
                        }
                }
            }
            __syncthreads();
            constexpr int CH = 64 * BN / 4 / 256;
            #pragma unroll
            for (int i = 0; i < CH; ++i) {
                const int idx = i * 256 + tid;
                const int row = (idx * 4) / BN, col = (idx * 4) % BN;
                *(float4*)((float*)Cout + (size_t)(m0 + pass * 64 + row) * N + n0 + col)
                    = *(const float4*)&stgf[idx * 4];
            }
        }
    }
}

template<int BN, int ACT, bool BIAS, int OUT>
__global__ __launch_bounds__(256) void gemm_bf16(const unsigned short* __restrict__ A,
                                                 const unsigned short* __restrict__ Wt,
                                                 const float* __restrict__ bias,
                                                 void* __restrict__ Cout,
                                                 int K, int N) {
    __shared__ char smem[BN == 128 ? 32768 : 24576];
    gemm_body<BN, ACT, BIAS, OUT>(smem, A, Wt, bias, Cout, K, N,
                                  blockIdx.x * 128, blockIdx.y * BN, threadIdx.x);
}

// merged Q (y<4) + KV (y>=4) projections, both from K=512, bf16 out
__global__ __launch_bounds__(256) void gemm_qkv(const unsigned short* __restrict__ qxA,
                                                const unsigned short* __restrict__ wq,
                                                unsigned short* __restrict__ Qo,
                                                const unsigned short* __restrict__ vcA,
                                                const unsigned short* __restrict__ wkv,
                                                unsigned short* __restrict__ KVo) {
    __shared__ char smem[32768];
    if (blockIdx.y < 4)
        gemm_body<128, 0, false, 1>(smem, qxA, wq, nullptr, Qo, 512, 512,
                                    blockIdx.x * 128, blockIdx.y * 128, threadIdx.x);
    else
        gemm_body<128, 0, false, 1>(smem, vcA, wkv, nullptr, KVo, 512, 1024,
                                    blockIdx.x * 128, (blockIdx.y - 4) * 128, threadIdx.x);
}

// merged keys2 (y==0, bf16) + values2 (y>=1, transposed valT) from pkvx, M=512
__global__ __launch_bounds__(256) void gemm_kv2(const unsigned short* __restrict__ pkvx,
                                                const unsigned short* __restrict__ wk2,
                                                const float* __restrict__ bk2,
                                                unsigned short* __restrict__ keys,
                                                const unsigned short* __restrict__ wv2,
                                                const float* __restrict__ bv2,
                                                unsigned short* __restrict__ valT) {
    __shared__ char smem[24576];
    if (blockIdx.y == 0)
        gemm_body<64, 1, true, 1>(smem, pkvx, wk2, bk2, keys, 512, 64,
                                  blockIdx.x * 128, 0, threadIdx.x);
    else
        gemm_body<64, 1, true, 2>(smem, pkvx, wv2, bv2, valT, 512, 1024,
                                  blockIdx.x * 128, (blockIdx.y - 1) * 64, threadIdx.x);
}

// ---------------- attention-1: one wave per row, us8 vectorized, head = lane>>3 ----------------
__global__ __launch_bounds__(256) void attn1_kernel(const unsigned short* __restrict__ Q,
                                                    const unsigned short* __restrict__ KV,
                                                    unsigned short* __restrict__ zbf) {
    const int w = threadIdx.x >> 6, lane = threadIdx.x & 63;
    const size_t row = (size_t)blockIdx.x * 4 + w;
    const int l = (int)(row & (L_ - 1));
    unsigned short* zr = zbf + row * 512 + lane * 8;
    if (l == 0) {
        us8 z;
        #pragma unroll
        for (int j = 0; j < 8; ++j) z[j] = 0;
        *(us8*)zr = z;
        return;
    }
    const us8 q8 = *(const us8*)(Q + row * 512 + lane * 8);
    const us8 k8 = *(const us8*)(KV + (row - 1) * 1024 + lane * 8);
    float p = 0.f;
    #pragma unroll
    for (int j = 0; j < 8; ++j) p += bf2f(q8[j]) * bf2f(k8[j]);
    p += __shfl_xor(p, 1); p += __shfl_xor(p, 2); p += __shfl_xor(p, 4);
    const float sig = 1.0f / (1.0f + expf(-p * 0.125f));
    const us8 v8 = *(const us8*)(KV + (row - 1) * 1024 + 512 + lane * 8);
    us8 o;
    #pragma unroll
    for (int j = 0; j < 8; ++j) o[j] = f2bf(sig * bf2f(v8[j]));
    *(us8*)zr = o;
}

// ---------------- fused residual + LayerNorm (optional bf16 mirror) ----------------
__global__ __launch_bounds__(256) void ln_kernel(const float* __restrict__ X,
                                                 const float* __restrict__ Y,
                                                 const float* __restrict__ g,
                                                 const float* __restrict__ beta,
                                                 float* __restrict__ out,
                                                 unsigned short* __restrict__ outb) {
    const int w = threadIdx.x >> 6, lane = threadIdx.x & 63;
    const size_t row = (size_t)blockIdx.x * 4 + w;
    const float4* x4 = (const float4*)(X + row * C_);
    const float4* y4 = (const float4*)(Y + row * C_);
    float v[8];
    const float4 a = x4[lane * 2 + 0], b2 = x4[lane * 2 + 1];
    const float4 c = y4[lane * 2 + 0], d = y4[lane * 2 + 1];
    v[0] = a.x + c.x; v[1] = a.y + c.y; v[2] = a.z + c.z; v[3] = a.w + c.w;
    v[4] = b2.x + d.x; v[5] = b2.y + d.y; v[6] = b2.z + d.z; v[7] = b2.w + d.w;
    float s = 0.f;
    #pragma unroll
    for (int j = 0; j < 8; ++j) s += v[j];
    #pragma unroll
    for (int o = 32; o; o >>= 1) s += __shfl_xor(s, o);
    const float mean = s * (1.0f / 512.0f);
    float q = 0.f;
    #pragma unroll
    for (int j = 0; j < 8; ++j) { const float t = v[j] - mean; q += t * t; }
    #pragma unroll
    for (int o = 32; o; o >>= 1) q += __shfl_xor(q, o);
    const float rstd = rsqrtf(q * (1.0f / 512.0f) + 1e-5f);
    const float4 g0 = ((const float4*)g)[lane * 2], g1 = ((const float4*)g)[lane * 2 + 1];
    const float4 bb0 = ((const float4*)beta)[lane * 2], bb1 = ((const float4*)beta)[lane * 2 + 1];
    float o8[8];
    o8[0] = (v[0] - mean) * rstd * g0.x + bb0.x;
    o8[1] = (v[1] - mean) * rstd * g0.y + bb0.y;
    o8[2] = (v[2] - mean) * rstd * g0.z + bb0.z;
    o8[3] = (v[3] - mean) * rstd * g0.w + bb0.w;
    o8[4] = (v[4] - mean) * rstd * g1.x + bb1.x;
    o8[5] = (v[5] - mean) * rstd * g1.y + bb1.y;
    o8[6] = (v[6] - mean) * rstd * g1.z + bb1.z;
    o8[7] = (v[7] - mean) * rstd * g1.w + bb1.w;
    float4 o0, o1;
    o0.x = o8[0]; o0.y = o8[1]; o0.z = o8[2]; o0.w = o8[3];
    o1.x = o8[4]; o1.y = o8[5]; o1.z = o8[6]; o1.w = o8[7];
    ((float4*)(out + row * C_))[lane * 2 + 0] = o0;
    ((float4*)(out + row * C_))[lane * 2 + 1] = o1;
    if (outb) {
        us8 pk;
        #pragma unroll
        for (int j = 0; j < 8; ++j) pk[j] = f2bf(o8[j]);
        *(us8*)(outb + row * C_ + lane * 8) = pk;
    }
}

// ---------------- masked softmax over L per (b,r) ----------------
__global__ __launch_bounds__(256) void psoftmax_kernel(const float* __restrict__ pscore,
                                                       const int* __restrict__ mask,
                                                       float* __restrict__ pAlpha) {
    const int r = blockIdx.x, b = blockIdx.y, t = threadIdx.x;
    __shared__ float red[256];
    float sv[8];
    float lm = -3.4e38f;
    #pragma unroll
    for (int i = 0; i < 8; ++i) {
        const int l = t + i * 256;
        float x = pscore[((size_t)b * L_ + l) * R_ + r];
        if (mask[(size_t)b * L_ + l] == 0) x = NEG_;
        sv[i] = x; lm = fmaxf(lm, x);
    }
    red[t] = lm; __syncthreads();
    for (int o = 128; o; o >>= 1) { if (t < o) red[t] = fmaxf(red[t], red[t + o]); __syncthreads(); }
    const float mx = red[0]; __syncthreads();
    float ls = 0.f;
    #pragma unroll
    for (int i = 0; i < 8; ++i) { sv[i] = expf(sv[i] - mx); ls += sv[i]; }
    red[t] = ls; __syncthreads();
    for (int o = 128; o; o >>= 1) { if (t < o) red[t] += red[t + o]; __syncthreads(); }
    const float inv = 1.0f / red[0];
    #pragma unroll
    for (int i = 0; i < 8; ++i)
        pAlpha[((size_t)b * L_ + t + i * 256) * R_ + r] = sv[i] * inv;
}

// ---------------- pkvx = pAlpha^T @ vx, K-split partials ----------------
__global__ __launch_bounds__(256) void pkv_partial_kernel(const float* __restrict__ pAlpha,
                                                          const float* __restrict__ vx,
                                                          float* __restrict__ part) {
    const int ct = blockIdx.x, ks = blockIdx.y, b = blockIdx.z;
    constexpr int KT = 16;
    __shared__ float Pa[KT][64 + 4];
    __shared__ float Vx[KT][64 + 4];
    const int tid = threadIdx.x;
    const int trow = tid >> 4, tcol = tid & 15;
    float acc[4][4];
    #pragma unroll
    for (int i = 0; i < 4; ++i)
        #pragma unroll
        for (int j = 0; j < 4; ++j) acc[i][j] = 0.f;
    const int l0 = ks * 256;
    for (int kk = 0; kk < 256; kk += KT) {
        const int lrow = tid >> 4;
        const int q4 = (tid & 15) << 2;
        const size_t lidx = (size_t)b * L_ + l0 + kk + lrow;
        *(float4*)&Pa[lrow][q4] = *(const float4*)(pAlpha + lidx * R_ + q4);
        *(float4*)&Vx[lrow][q4] = *(const float4*)(vx + lidx * C_ + ct * 64 + q4);
        __syncthreads();
        #pragma unroll
        for (int k = 0; k < KT; ++k) {
            float a[4], v[4];
            *(float4*)&a[0] = *(const float4*)&Pa[k][trow * 4];
            *(float4*)&v[0] = *(const float4*)&Vx[k][tcol * 4];
            #pragma unroll
            for (int i = 0; i < 4; ++i)
                #pragma unroll
                for (int j = 0; j < 4; ++j)
                    acc[i][j] = fmaf(a[i], v[j], acc[i][j]);
        }
        __syncthreads();
    }
    #pragma unroll
    for (int i = 0; i < 4; ++i) {
        const int r = trow * 4 + i;
        float4 vv;
        vv.x = acc[i][0]; vv.y = acc[i][1]; vv.z = acc[i][2]; vv.w = acc[i][3];
        *(float4*)(part + (((size_t)b * 8 + ks) * R_ + r) * C_ + ct * 64 + tcol * 4) = vv;
    }
}

__global__ __launch_bounds__(256) void pkv_reduce_kernel(const float* __restrict__ part,
                                                         unsigned short* __restrict__ pkvx) {
    const size_t idx = (size_t)blockIdx.x * 256 + threadIdx.x;
    const size_t b = idx / ((size_t)R_ * C_);
    const size_t rem = idx % ((size_t)R_ * C_);
    float s = 0.f;
    #pragma unroll
    for (int ks = 0; ks < 8; ++ks) s += part[(b * 8 + ks) * ((size_t)R_ * C_) + rem];
    pkvx[idx] = f2bf(s);
}

// ---------------- attention-2 fused, MFMA ----------------
__global__ __launch_bounds__(256) void attn2_kernel(const unsigned short* __restrict__ q,
                                                    const unsigned short* __restrict__ k,
                                                    const unsigned short* __restrict__ vT,
                                                    const unsigned short* __restrict__ gate,
                                                    unsigned short* __restrict__ hb) {
    const int b = blockIdx.y, l0 = blockIdx.x * 32;
    const int tid = threadIdx.x, w = tid >> 6, lane = tid & 63;
    __shared__ float sc_s[32][68];
    __shared__ unsigned short al_s[32][72];

    {
        f32x4v acc[2];
        acc[0] = f32x4v{0.f,0.f,0.f,0.f}; acc[1] = f32x4v{0.f,0.f,0.f,0.f};
        const int r0 = w * 16;
        #pragma unroll
        for (int kk = 0; kk < 2; ++kk) {
            const bf16x8 bfr = *(const bf16x8*)(k + ((size_t)b * 64 + r0 + (lane & 15)) * 64 + kk * 32 + (lane >> 4) * 8);
            #pragma unroll
            for (int m = 0; m < 2; ++m) {
                const bf16x8 af = *(const bf16x8*)(q + ((size_t)b * L_ + l0 + m * 16 + (lane & 15)) * 64 + kk * 32 + (lane >> 4) * 8);
                acc[m] = __builtin_amdgcn_mfma_f32_16x16x32_bf16(af, bfr, acc[m], 0, 0, 0);
            }
        }
        #pragma unroll
        for (int m = 0; m < 2; ++m)
            #pragma unroll
            for (int i = 0; i < 4; ++i)
                sc_s[m * 16 + (lane >> 4) * 4 + i][r0 + (lane & 15)] = acc[m][i];
    }
    __syncthreads();
    {
        const int t = tid >> 3, rg = tid & 7;
        float v[8];
        float mx = -3.4e38f;
        #pragma unroll
        for (int j = 0; j < 8; ++j) { v[j] = sc_s[t][rg * 8 + j] * 0.125f; mx = fmaxf(mx, v[j]); }
        #pragma unroll
        for (int o = 1; o < 8; o <<= 1) mx = fmaxf(mx, __shfl_xor(mx, o));
        float es = 0.f;
        #pragma unroll
        for (int j = 0; j < 8; ++j) { v[j] = expf(v[j] - mx); es += v[j]; }
        #pragma unroll
        for (int o = 1; o < 8; o <<= 1) es += __shfl_xor(es, o);
        const float inv = 1.0f / es;
        #pragma unroll
        for (int j = 0; j < 8; ++j) al_s[t][rg * 8 + j] = f2bf(v[j] * inv);
    }
    __syncthreads();
    bf16x8 bl[2][2];
    #pragma unroll
    for (int n = 0; n < 2; ++n)
        #pragma unroll
        for (int kk = 0; kk < 2; ++kk)
            bl[n][kk] = *(const bf16x8*)&al_s[n * 16 + (lane & 15)][kk * 32 + (lane >> 4) * 8];
    const int hbase = w * 256;
    #pragma unroll 4
    for (int mi = 0; mi < 16; ++mi) {
        const int h0 = hbase + mi * 16;
        const unsigned short* ap = vT + ((size_t)b * H_ + h0 + (lane & 15)) * 64 + (lane >> 4) * 8;
        const bf16x8 a0 = *(const bf16x8*)(ap);
        const bf16x8 a1 = *(const bf16x8*)(ap + 32);
        f32x4v acc[2];
        acc[0] = f32x4v{0.f,0.f,0.f,0.f}; acc[1] = f32x4v{0.f,0.f,0.f,0.f};
        #pragma unroll
        for (int n = 0; n < 2; ++n) {
            acc[n] = __builtin_amdgcn_mfma_f32_16x16x32_bf16(a0, bl[n][0], acc[n], 0, 0, 0);
            acc[n] = __builtin_amdgcn_mfma_f32_16x16x32_bf16(a1, bl[n][1], acc[n], 0, 0, 0);
        }
        #pragma unroll
        for (int n = 0; n < 2; ++n) {
            const size_t base = ((size_t)b * L_ + l0 + n * 16 + (lane & 15)) * H_ + h0 + (lane >> 4) * 4;
            const ushort4 g = *(const ushort4*)(gate + base);
            ushort4 o;
            o.x = f2bf(bf2f(g.x) * acc[n][0]);
            o.y = f2bf(bf2f(g.y) * acc[n][1]);
            o.z = f2bf(bf2f(g.z) * acc[n][2]);
            o.w = f2bf(bf2f(g.w) * acc[n][3]);
            *(ushort4*)(hb + base) = o;
        }
    }
}

// ---------------- launch ----------------
extern "C" void kernel_launch(void* const* d_in, const int* in_sizes, int n_in,
                              void* d_out, int out_size, void* d_ws, size_t ws_size,
                              hipStream_t stream) {
    const float* qx   = (const float*)d_in[0];
    const float* vx   = (const float*)d_in[1];
    const int*   maskPAD2 = (const int*)d_in[2];
    const float* WQ1  = (const float*)d_in[3];
    const float* WK1  = (const float*)d_in[4];
    const float* WV1  = (const float*)d_in[5];
    const float* WO1  = (const float*)d_in[6];
    const float* qln_g = (const float*)d_in[7];
    const float* qln_b = (const float*)d_in[8];
    const float* Wp   = (const float*)d_in[9];
    const float* bp   = (const float*)d_in[10];
    const float* Wq2  = (const float*)d_in[11];
    const float* bq2  = (const float*)d_in[12];
    const float* Wk2  = (const float*)d_in[13];
    const float* bk2  = (const float*)d_in[14];
    const float* Wv2  = (const float*)d_in[15];
    const float* bv2  = (const float*)d_in[16];
    const float* Wu   = (const float*)d_in[17];
    const float* bu   = (const float*)d_in[18];
    const float* Wo2  = (const float*)d_in[19];
    const float* bo2  = (const float*)d_in[20];
    const float* ln_g = (const float*)d_in[21];
    const float* ln_b = (const float*)d_in[22];
    float* out = (float*)d_out;

    // ---- workspace layout ----
    char* p = (char*)d_ws;
    const size_t NC2 = (size_t)N_ * C_ * 2;          // 16.78 MB
    unsigned short* qx_bf = (unsigned short*)p; p += NC2;         // -> zin_bf -> h_bf[0:half]
    unsigned short* Q_bf  = (unsigned short*)p; p += NC2;         // -> h_bf[half:]
    unsigned short* KV_bf = (unsigned short*)p; p += 2 * NC2;     // -> gate
    unsigned short* vc_bf = (unsigned short*)p; p += NC2;         // -> qx1_bf
    float* t1    = (float*)p; p += (size_t)N_ * C_ * 4;           // -> t2
    float* qx1f  = (float*)p; p += (size_t)N_ * C_ * 4;
    unsigned short* vx_bf = (unsigned short*)p; p += NC2;
    float* pscore  = (float*)p; p += (size_t)N_ * R_ * 4;
    float* pAlpha  = (float*)p; p += (size_t)N_ * R_ * 4;
    unsigned short* queries = (unsigned short*)p; p += (size_t)N_ * DK_ * 2;
    unsigned short* keysB   = (unsigned short*)p; p += (size_t)B_ * R_ * DK_ * 2;
    unsigned short* valT    = (unsigned short*)p; p += (size_t)B_ * H_ * R_ * 2;
    unsigned short* pkvx_bf = (unsigned short*)p; p += (size_t)B_ * R_ * C_ * 2;
    float* part    = (float*)p; p += (size_t)B_ * 8 * R_ * C_ * 4;
    float* segsum  = (float*)p; p += (size_t)B_ * NSEG * C_ * 4;
    unsigned short* wq1t  = (unsigned short*)p; p += (size_t)512 * C_ * 2;
    unsigned short* wkv1t = (unsigned short*)p; p += (size_t)1024 * C_ * 2;
    unsigned short* wo1t  = (unsigned short*)p; p += (size_t)C_ * 512 * 2;
    unsigned short* wpt   = (unsigned short*)p; p += (size_t)R_ * C_ * 2;
    unsigned short* wq2t  = (unsigned short*)p; p += (size_t)DK_ * C_ * 2;
    unsigned short* wk2t  = (unsigned short*)p; p += (size_t)DK_ * C_ * 2;
    unsigned short* wv2t  = (unsigned short*)p; p += (size_t)H_ * C_ * 2;
    unsigned short* wut   = (unsigned short*)p; p += (size_t)H_ * C_ * 2;
    unsigned short* wo2t  = (unsigned short*)p; p += (size_t)C_ * H_ * 2;

    unsigned short* zin_bf = qx_bf;       // qx_bf dead after Q gemm
    unsigned short* h_bf   = qx_bf;       // spans qx_bf + Q_bf
    unsigned short* gate   = KV_bf;       // KV dead after attn1
    unsigned short* qx1_bf = vc_bf;       // vc dead after KV gemm
    float* t2 = t1;

    // 1) conversions + weight prep
    cvt2_kernel<<<dim3((N_ * C_) / (256 * 8), 1, 2), 256, 0, stream>>>(qx, vx, qx_bf, vx_bf);
    WtArgs wa;
    wa.d[0] = {WQ1, wq1t, 512, 512};
    wa.d[1] = {WK1, wkv1t, 512, 512};
    wa.d[2] = {WV1, wkv1t + (size_t)512 * 512, 512, 512};
    wa.d[3] = {WO1, wo1t, 512, 512};
    wa.d[4] = {Wp,  wpt,  512, 64};
    wa.d[5] = {Wq2, wq2t, 512, 64};
    wa.d[6] = {Wk2, wk2t, 512, 64};
    wa.d[7] = {Wv2, wv2t, 512, 1024};
    wa.d[8] = {Wu,  wut,  512, 1024};
    wa.d[9] = {Wo2, wo2t, 1024, 512};
    wtrans_all_kernel<<<dim3(32, 32, 10), dim3(32, 8), 0, stream>>>(wa);
    // 2) running mean (bf16)
    seg_sum_kernel<<<dim3(NSEG, B_), 512, 0, stream>>>(qx_bf, segsum);
    seg_scan_kernel<<<dim3(NSEG, B_), 512, 0, stream>>>(qx_bf, segsum, vc_bf);
    // 3) merged Q + KV projections
    gemm_qkv<<<dim3(N_ / 128, 12), 256, 0, stream>>>(qx_bf, wq1t, Q_bf, vc_bf, wkv1t, KV_bf);
    // 4) attn1 -> zin (bf16, overwrites qx_bf)
    attn1_kernel<<<N_ / 4, 256, 0, stream>>>(Q_bf, KV_bf, zin_bf);
    // 5) WO1 -> t1 f32
    gemm_bf16<128, 0, false, 0><<<dim3(N_ / 128, 4), 256, 0, stream>>>(zin_bf, wo1t, nullptr, t1, 512, 512);
    // 6) qx1 = LN(qx + t1)
    ln_kernel<<<N_ / 4, 256, 0, stream>>>(qx, t1, qln_g, qln_b, qx1f, qx1_bf);
    // 7) gate = silu(qx1 @ Wu + bu)
    gemm_bf16<128, 1, true, 1><<<dim3(N_ / 128, 8), 256, 0, stream>>>(qx1_bf, wut, bu, gate, 512, 1024);
    // 8) pseudo-attn
    gemm_bf16<64, 0, true, 0><<<dim3(N_ / 128, 1), 256, 0, stream>>>(vx_bf, wpt, bp, pscore, 512, 64);
    psoftmax_kernel<<<dim3(R_, B_), 256, 0, stream>>>(pscore, maskPAD2, pAlpha);
    pkv_partial_kernel<<<dim3(8, 8, B_), 256, 0, stream>>>(pAlpha, vx, part);
    pkv_reduce_kernel<<<(B_ * R_ * C_) / 256, 256, 0, stream>>>(part, pkvx_bf);
    // 9) queries; merged keys2 + values2(valT)
    gemm_bf16<64, 1, true, 1><<<dim3(N_ / 128, 1), 256, 0, stream>>>(qx1_bf, wq2t, bq2, queries, 512, 64);
    gemm_kv2<<<dim3((B_ * R_) / 128, 17), 256, 0, stream>>>(pkvx_bf, wk2t, bk2, keysB, wv2t, bv2, valT);
    // 10) fused attn2 -> h bf16
    attn2_kernel<<<dim3(L_ / 32, B_), 256, 0, stream>>>(queries, keysB, valT, gate, h_bf);
    // 11) t2 = h @ Wo2 + bo2 ; out = LN(qx1 + t2)
    gemm_bf16<128, 0, true, 0><<<dim3(N_ / 128, 4), 256, 0, stream>>>(h_bf, wo2t, bo2, t2, 1024, 512);
    ln_kernel<<<N_ / 4, 256, 0, stream>>>(qx1f, t2, ln_g, ln_b, out, nullptr);
}

// Round 8
// 447.438 us; speedup vs baseline: 3.1345x; 1.0173x over previous
//
#include <hip/hip_runtime.h>
#include <hip/hip_bf16.h>

#define B_ 8
#define L_ 2048
#define C_ 512
#define DK_ 64
#define M_ 8
#define R_ 64
#define H_ 1024
#define N_ (B_*L_)
#define NEG_ (-32767.0f)
#define NSEG 32
#define SEGLEN 64

typedef short bf16x8 __attribute__((ext_vector_type(8)));
typedef unsigned short us8 __attribute__((ext_vector_type(8)));
typedef float f32x4v __attribute__((ext_vector_type(4)));

__device__ __forceinline__ float siluf_(float x) { return x / (1.0f + expf(-x)); }

__device__ __forceinline__ unsigned short f2bf(float f) {
    __hip_bfloat16 h = __float2bfloat16(f);
    return __builtin_bit_cast(unsigned short, h);
}
__device__ __forceinline__ float bf2f(unsigned short u) {
    unsigned v = (unsigned)u << 16;
    return __builtin_bit_cast(float, v);
}

// async global->LDS, 16B per lane; LDS dest = wave base + lane*16 (linear)
__device__ __forceinline__ void gload_lds16(const void* g, void* l) {
    __builtin_amdgcn_global_load_lds(
        (const __attribute__((address_space(1))) unsigned int*)(uintptr_t)g,
        (__attribute__((address_space(3))) unsigned int*)(unsigned)(uintptr_t)l,
        16, 0, 0);
}

// ---------------- qx prep: fp32 -> bf16 + per-segment sums (merged cvt+seg_sum) ----------------
__global__ __launch_bounds__(512) void qxprep_kernel(const float* __restrict__ qx,
                                                     unsigned short* __restrict__ qx_bf,
                                                     float* __restrict__ segsum) {
    const int seg = blockIdx.x, b = blockIdx.y, c = threadIdx.x;
    const size_t base = ((size_t)b * L_ + (size_t)seg * SEGLEN) * C_ + c;
    const float* p = qx + base;
    unsigned short* o = qx_bf + base;
    float s = 0.f;
    #pragma unroll 8
    for (int i = 0; i < SEGLEN; ++i) {
        const float v = p[(size_t)i * C_];
        s += v;
        o[(size_t)i * C_] = f2bf(v);
    }
    segsum[((size_t)b * NSEG + seg) * C_ + c] = s;
}

// ---------------- fp32 -> bf16 (vx only) ----------------
__global__ __launch_bounds__(256) void cvt_kernel(const float* __restrict__ s,
                                                  unsigned short* __restrict__ d) {
    const size_t i = ((size_t)blockIdx.x * 256 + threadIdx.x) * 8;
    const float4 v0 = *(const float4*)(s + i);
    const float4 v1 = *(const float4*)(s + i + 4);
    us8 o;
    o[0] = f2bf(v0.x); o[1] = f2bf(v0.y); o[2] = f2bf(v0.z); o[3] = f2bf(v0.w);
    o[4] = f2bf(v1.x); o[5] = f2bf(v1.y); o[6] = f2bf(v1.z); o[7] = f2bf(v1.w);
    *(us8*)(d + i) = o;
}

// ---------------- batched weight transpose+convert: W[K][N] f32 -> Wt[N][K] bf16 ----------------
struct WtDesc { const float* src; unsigned short* dst; int K; int N; };
struct WtArgs { WtDesc d[10]; };

__global__ __launch_bounds__(256) void wtrans_all_kernel(WtArgs a) {
    const WtDesc w = a.d[blockIdx.z];
    const int n0 = blockIdx.x * 32, k0 = blockIdx.y * 32;
    if (n0 >= w.N || k0 >= w.K) return;
    __shared__ float t[32][33];
    const int tx = threadIdx.x, ty = threadIdx.y;
    #pragma unroll
    for (int i = 0; i < 32; i += 8)
        t[ty + i][tx] = w.src[(size_t)(k0 + ty + i) * w.N + n0 + tx];
    __syncthreads();
    #pragma unroll
    for (int i = 0; i < 32; i += 8)
        w.dst[(size_t)(n0 + ty + i) * w.K + k0 + tx] = f2bf(t[tx][ty + i]);
}

// ---------------- segmented scan (running mean), bf16 in/out ----------------
__global__ __launch_bounds__(512) void seg_scan_kernel(const unsigned short* __restrict__ qx,
                                                       const float* __restrict__ segsum,
                                                       unsigned short* __restrict__ vc) {
    const int seg = blockIdx.x, b = blockIdx.y, c = threadIdx.x;
    float off = 0.f;
    for (int s = 0; s < seg; ++s) off += segsum[((size_t)b * NSEG + s) * C_ + c];
    const unsigned short* p = qx + ((size_t)b * L_ + (size_t)seg * SEGLEN) * C_ + c;
    unsigned short* o = vc + ((size_t)b * L_ + (size_t)seg * SEGLEN) * C_ + c;
    float run = off;
    for (int i = 0; i < SEGLEN; ++i) {
        run += bf2f(p[(size_t)i * C_]);
        const int l = seg * SEGLEN + i;
        o[(size_t)i * C_] = f2bf(run / (float)(l + 1));
    }
}

// ---------------- bf16 MFMA GEMM body (m97 structure + LDS-staged epilogue) ----------------
// A[M][K] bf16, Wt[N][K] bf16. OUT: 0 = f32 row-major (2-pass f32 stage),
// 1 = bf16 row-major (us8 stage), 2 = bf16 transposed-by-64 valT (BN=64 only).
template<int BN, int ACT, bool BIAS, int OUT>
__device__ __forceinline__ void gemm_body(char* smem,
        const unsigned short* __restrict__ A, const unsigned short* __restrict__ Wt,
        const float* __restrict__ bias, void* __restrict__ Cout,
        int K, int N, int m0, int n0, int tid) {
    constexpr int BK = 64;
    constexpr int WN = BN / 2;
    constexpr int TN = WN / 16;
    unsigned short* Alds = (unsigned short*)smem;             // 128*64 us = 16KB
    unsigned short* Blds = (unsigned short*)(smem + 16384);   // BN*64 us
    const int w = tid >> 6, lane = tid & 63;
    const int wm = w >> 1, wn = w & 1;

    f32x4v acc[4][TN];
    #pragma unroll
    for (int m = 0; m < 4; ++m)
        #pragma unroll
        for (int n = 0; n < TN; ++n)
            acc[m][n] = f32x4v{0.f, 0.f, 0.f, 0.f};

    const int lrow = lane >> 3;
    const int lk = (lane & 7) * 8;

    for (int k0 = 0; k0 < K; k0 += BK) {
        __syncthreads();
        #pragma unroll
        for (int i = 0; i < 4; ++i) {
            const int c = w * 4 + i;
            const int row = c * 8 + lrow;
            gload_lds16(A + (size_t)(m0 + row) * K + k0 + lk, (char*)Alds + c * 1024);
        }
        #pragma unroll
        for (int i = 0; i < BN / 32; ++i) {
            const int c = w * (BN / 32) + i;
            const int col = c * 8 + lrow;
            gload_lds16(Wt + (size_t)(n0 + col) * K + k0 + lk, (char*)Blds + c * 1024);
        }
        __syncthreads();
        #pragma unroll
        for (int kk = 0; kk < 2; ++kk) {
            const int ko = kk * 64 + (lane >> 4) * 16;
            bf16x8 af[4], bfr[TN];
            #pragma unroll
            for (int m = 0; m < 4; ++m)
                af[m] = *(const bf16x8*)((const char*)Alds + (wm * 64 + m * 16 + (lane & 15)) * 128 + ko);
            #pragma unroll
            for (int n = 0; n < TN; ++n)
                bfr[n] = *(const bf16x8*)((const char*)Blds + (wn * WN + n * 16 + (lane & 15)) * 128 + ko);
            #pragma unroll
            for (int m = 0; m < 4; ++m)
                #pragma unroll
                for (int n = 0; n < TN; ++n)
                    acc[m][n] = __builtin_amdgcn_mfma_f32_16x16x32_bf16(af[m], bfr[n], acc[m][n], 0, 0, 0);
        }
    }

    // bias per n-frag (col fixed per lane)
    const int r0 = (lane >> 4) * 4;
    float bv[TN];
    #pragma unroll
    for (int n = 0; n < TN; ++n)
        bv[n] = BIAS ? bias[n0 + wn * WN + n * 16 + (lane & 15)] : 0.f;

    if constexpr (OUT == 1) {
        __syncthreads();                                  // all MFMA LDS reads done
        unsigned short* stg = (unsigned short*)smem;      // [128][BN]
        #pragma unroll
        for (int n = 0; n < TN; ++n) {
            const int cl = wn * WN + n * 16 + (lane & 15);
            #pragma unroll
            for (int m = 0; m < 4; ++m)
                #pragma unroll
                for (int r = 0; r < 4; ++r) {
                    float val = acc[m][n][r] + bv[n];
                    if constexpr (ACT == 1) val = siluf_(val);
                    stg[(wm * 64 + m * 16 + r0 + r) * BN + cl] = f2bf(val);
                }
        }
        __syncthreads();
        constexpr int CH = 128 * BN / 8 / 256;
        #pragma unroll
        for (int i = 0; i < CH; ++i) {
            const int idx = i * 256 + tid;
            const int row = (idx * 8) / BN, col = (idx * 8) % BN;
            *(us8*)((unsigned short*)Cout + (size_t)(m0 + row) * N + n0 + col) = *(const us8*)&stg[idx * 8];
        }
    } else if constexpr (OUT == 2) {
        // BN==64 only. stage [2*BN][72] us (pad 8 for alignment+banks)
        __syncthreads();
        unsigned short* stg = (unsigned short*)smem;
        #pragma unroll
        for (int n = 0; n < TN; ++n) {
            const int cl = wn * WN + n * 16 + (lane & 15);
            #pragma unroll
            for (int m = 0; m < 4; ++m)
                #pragma unroll
                for (int r = 0; r < 4; ++r) {
                    float val = acc[m][n][r] + bv[n];
                    if constexpr (ACT == 1) val = siluf_(val);
                    stg[(wm * BN + cl) * 72 + m * 16 + r0 + r] = f2bf(val);
                }
        }
        __syncthreads();
        constexpr int CH = 2 * BN * 64 / 8 / 256;
        #pragma unroll
        for (int i = 0; i < CH; ++i) {
            const int idx = i * 256 + tid;
            const int vrow = idx >> 3, j = (idx & 7) * 8;
            const int h = vrow >= BN ? 1 : 0;
            const int col = vrow & (BN - 1);
            *(us8*)((unsigned short*)Cout + (((size_t)(m0 >> 6) + h) * N + n0 + col) * 64 + j)
                = *(const us8*)&stg[vrow * 72 + j];
        }
    } else {
        // OUT==0: f32 row-major, two 64-row passes through a [64][BN] f32 stage
        float* stgf = (float*)smem;
        #pragma unroll
        for (int pass = 0; pass < 2; ++pass) {
            __syncthreads();
            if (wm == pass) {
                #pragma unroll
                for (int n = 0; n < TN; ++n) {
                    const int cl = wn * WN + n * 16 + (lane & 15);
                    #pragma unroll
                    for (int m = 0; m < 4; ++m)
                        #pragma unroll
                        for (int r = 0; r < 4; ++r) {
                            float val = acc[m][n][r] + bv[n];
                            if constexpr (ACT == 1) val = siluf_(val);
                            stgf[(m * 16 + r0 + r) * BN + cl] = val;
                        }
                }
            }
            __syncthreads();
            constexpr int CH = 64 * BN / 4 / 256;
            #pragma unroll
            for (int i = 0; i < CH; ++i) {
                const int idx = i * 256 + tid;
                const int row = (idx * 4) / BN, col = (idx * 4) % BN;
                *(float4*)((float*)Cout + (size_t)(m0 + pass * 64 + row) * N + n0 + col)
                    = *(const float4*)&stgf[idx * 4];
            }
        }
    }
}

template<int BN, int ACT, bool BIAS, int OUT>
__global__ __launch_bounds__(256) void gemm_bf16(const unsigned short* __restrict__ A,
                                                 const unsigned short* __restrict__ Wt,
                                                 const float* __restrict__ bias,
                                                 void* __restrict__ Cout,
                                                 int K, int N) {
    __shared__ char smem[BN == 128 ? 32768 : 24576];
    gemm_body<BN, ACT, BIAS, OUT>(smem, A, Wt, bias, Cout, K, N,
                                  blockIdx.x * 128, blockIdx.y * BN, threadIdx.x);
}

// merged Q (y<4) + KV (y>=4) projections, both from K=512, bf16 out
__global__ __launch_bounds__(256) void gemm_qkv(const unsigned short* __restrict__ qxA,
                                                const unsigned short* __restrict__ wq,
                                                unsigned short* __restrict__ Qo,
                                                const unsigned short* __restrict__ vcA,
                                                const unsigned short* __restrict__ wkv,
                                                unsigned short* __restrict__ KVo) {
    __shared__ char smem[32768];
    if (blockIdx.y < 4)
        gemm_body<128, 0, false, 1>(smem, qxA, wq, nullptr, Qo, 512, 512,
                                    blockIdx.x * 128, blockIdx.y * 128, threadIdx.x);
    else
        gemm_body<128, 0, false, 1>(smem, vcA, wkv, nullptr, KVo, 512, 1024,
                                    blockIdx.x * 128, (blockIdx.y - 4) * 128, threadIdx.x);
}

// merged keys2 (y==0, bf16) + values2 (y>=1, transposed valT) from pkvx, M=512
__global__ __launch_bounds__(256) void gemm_kv2(const unsigned short* __restrict__ pkvx,
                                                const unsigned short* __restrict__ wk2,
                                                const float* __restrict__ bk2,
                                                unsigned short* __restrict__ keys,
                                                const unsigned short* __restrict__ wv2,
                                                const float* __restrict__ bv2,
                                                unsigned short* __restrict__ valT) {
    __shared__ char smem[24576];
    if (blockIdx.y == 0)
        gemm_body<64, 1, true, 1>(smem, pkvx, wk2, bk2, keys, 512, 64,
                                  blockIdx.x * 128, 0, threadIdx.x);
    else
        gemm_body<64, 1, true, 2>(smem, pkvx, wv2, bv2, valT, 512, 1024,
                                  blockIdx.x * 128, (blockIdx.y - 1) * 64, threadIdx.x);
}

// ---------------- attention-1: one wave per row, us8 vectorized, head = lane>>3 ----------------
__global__ __launch_bounds__(256) void attn1_kernel(const unsigned short* __restrict__ Q,
                                                    const unsigned short* __restrict__ KV,
                                                    unsigned short* __restrict__ zbf) {
    const int w = threadIdx.x >> 6, lane = threadIdx.x & 63;
    const size_t row = (size_t)blockIdx.x * 4 + w;
    const int l = (int)(row & (L_ - 1));
    unsigned short* zr = zbf + row * 512 + lane * 8;
    if (l == 0) {
        us8 z;
        #pragma unroll
        for (int j = 0; j < 8; ++j) z[j] = 0;
        *(us8*)zr = z;
        return;
    }
    const us8 q8 = *(const us8*)(Q + row * 512 + lane * 8);
    const us8 k8 = *(const us8*)(KV + (row - 1) * 1024 + lane * 8);
    float p = 0.f;
    #pragma unroll
    for (int j = 0; j < 8; ++j) p += bf2f(q8[j]) * bf2f(k8[j]);
    p += __shfl_xor(p, 1); p += __shfl_xor(p, 2); p += __shfl_xor(p, 4);
    const float sig = 1.0f / (1.0f + expf(-p * 0.125f));
    const us8 v8 = *(const us8*)(KV + (row - 1) * 1024 + 512 + lane * 8);
    us8 o;
    #pragma unroll
    for (int j = 0; j < 8; ++j) o[j] = f2bf(sig * bf2f(v8[j]));
    *(us8*)zr = o;
}

// ---------------- fused residual + LayerNorm (optional bf16 mirror) ----------------
__global__ __launch_bounds__(256) void ln_kernel(const float* __restrict__ X,
                                                 const float* __restrict__ Y,
                                                 const float* __restrict__ g,
                                                 const float* __restrict__ beta,
                                                 float* __restrict__ out,
                                                 unsigned short* __restrict__ outb) {
    const int w = threadIdx.x >> 6, lane = threadIdx.x & 63;
    const size_t row = (size_t)blockIdx.x * 4 + w;
    const float4* x4 = (const float4*)(X + row * C_);
    const float4* y4 = (const float4*)(Y + row * C_);
    float v[8];
    const float4 a = x4[lane * 2 + 0], b2 = x4[lane * 2 + 1];
    const float4 c = y4[lane * 2 + 0], d = y4[lane * 2 + 1];
    v[0] = a.x + c.x; v[1] = a.y + c.y; v[2] = a.z + c.z; v[3] = a.w + c.w;
    v[4] = b2.x + d.x; v[5] = b2.y + d.y; v[6] = b2.z + d.z; v[7] = b2.w + d.w;
    float s = 0.f;
    #pragma unroll
    for (int j = 0; j < 8; ++j) s += v[j];
    #pragma unroll
    for (int o = 32; o; o >>= 1) s += __shfl_xor(s, o);
    const float mean = s * (1.0f / 512.0f);
    float q = 0.f;
    #pragma unroll
    for (int j = 0; j < 8; ++j) { const float t = v[j] - mean; q += t * t; }
    #pragma unroll
    for (int o = 32; o; o >>= 1) q += __shfl_xor(q, o);
    const float rstd = rsqrtf(q * (1.0f / 512.0f) + 1e-5f);
    const float4 g0 = ((const float4*)g)[lane * 2], g1 = ((const float4*)g)[lane * 2 + 1];
    const float4 bb0 = ((const float4*)beta)[lane * 2], bb1 = ((const float4*)beta)[lane * 2 + 1];
    float o8[8];
    o8[0] = (v[0] - mean) * rstd * g0.x + bb0.x;
    o8[1] = (v[1] - mean) * rstd * g0.y + bb0.y;
    o8[2] = (v[2] - mean) * rstd * g0.z + bb0.z;
    o8[3] = (v[3] - mean) * rstd * g0.w + bb0.w;
    o8[4] = (v[4] - mean) * rstd * g1.x + bb1.x;
    o8[5] = (v[5] - mean) * rstd * g1.y + bb1.y;
    o8[6] = (v[6] - mean) * rstd * g1.z + bb1.z;
    o8[7] = (v[7] - mean) * rstd * g1.w + bb1.w;
    float4 o0, o1;
    o0.x = o8[0]; o0.y = o8[1]; o0.z = o8[2]; o0.w = o8[3];
    o1.x = o8[4]; o1.y = o8[5]; o1.z = o8[6]; o1.w = o8[7];
    ((float4*)(out + row * C_))[lane * 2 + 0] = o0;
    ((float4*)(out + row * C_))[lane * 2 + 1] = o1;
    if (outb) {
        us8 pk;
        #pragma unroll
        for (int j = 0; j < 8; ++j) pk[j] = f2bf(o8[j]);
        *(us8*)(outb + row * C_ + lane * 8) = pk;
    }
}

// ---------------- masked softmax over L per (b,r) ----------------
__global__ __launch_bounds__(256) void psoftmax_kernel(const float* __restrict__ pscore,
                                                       const int* __restrict__ mask,
                                                       float* __restrict__ pAlpha) {
    const int r = blockIdx.x, b = blockIdx.y, t = threadIdx.x;
    __shared__ float red[256];
    float sv[8];
    float lm = -3.4e38f;
    #pragma unroll
    for (int i = 0; i < 8; ++i) {
        const int l = t + i * 256;
        float x = pscore[((size_t)b * L_ + l) * R_ + r];
        if (mask[(size_t)b * L_ + l] == 0) x = NEG_;
        sv[i] = x; lm = fmaxf(lm, x);
    }
    red[t] = lm; __syncthreads();
    for (int o = 128; o; o >>= 1) { if (t < o) red[t] = fmaxf(red[t], red[t + o]); __syncthreads(); }
    const float mx = red[0]; __syncthreads();
    float ls = 0.f;
    #pragma unroll
    for (int i = 0; i < 8; ++i) { sv[i] = expf(sv[i] - mx); ls += sv[i]; }
    red[t] = ls; __syncthreads();
    for (int o = 128; o; o >>= 1) { if (t < o) red[t] += red[t + o]; __syncthreads(); }
    const float inv = 1.0f / red[0];
    #pragma unroll
    for (int i = 0; i < 8; ++i)
        pAlpha[((size_t)b * L_ + t + i * 256) * R_ + r] = sv[i] * inv;
}

// ---------------- pkvx = pAlpha^T @ vx (bf16), K-split partials ----------------
__global__ __launch_bounds__(256) void pkv_partial_kernel(const float* __restrict__ pAlpha,
                                                          const unsigned short* __restrict__ vx,
                                                          float* __restrict__ part) {
    const int ct = blockIdx.x, ks = blockIdx.y, b = blockIdx.z;
    constexpr int KT = 16;
    __shared__ float Pa[KT][64 + 4];
    __shared__ float Vx[KT][64 + 4];
    const int tid = threadIdx.x;
    const int trow = tid >> 4, tcol = tid & 15;
    float acc[4][4];
    #pragma unroll
    for (int i = 0; i < 4; ++i)
        #pragma unroll
        for (int j = 0; j < 4; ++j) acc[i][j] = 0.f;
    const int l0 = ks * 256;
    for (int kk = 0; kk < 256; kk += KT) {
        const int lrow = tid >> 4;
        const int q4 = (tid & 15) << 2;
        const size_t lidx = (size_t)b * L_ + l0 + kk + lrow;
        *(float4*)&Pa[lrow][q4] = *(const float4*)(pAlpha + lidx * R_ + q4);
        const ushort4 vv4 = *(const ushort4*)(vx + lidx * C_ + ct * 64 + q4);
        Vx[lrow][q4 + 0] = bf2f(vv4.x);
        Vx[lrow][q4 + 1] = bf2f(vv4.y);
        Vx[lrow][q4 + 2] = bf2f(vv4.z);
        Vx[lrow][q4 + 3] = bf2f(vv4.w);
        __syncthreads();
        #pragma unroll
        for (int k = 0; k < KT; ++k) {
            float a[4], v[4];
            *(float4*)&a[0] = *(const float4*)&Pa[k][trow * 4];
            *(float4*)&v[0] = *(const float4*)&Vx[k][tcol * 4];
            #pragma unroll
            for (int i = 0; i < 4; ++i)
                #pragma unroll
                for (int j = 0; j < 4; ++j)
                    acc[i][j] = fmaf(a[i], v[j], acc[i][j]);
        }
        __syncthreads();
    }
    #pragma unroll
    for (int i = 0; i < 4; ++i) {
        const int r = trow * 4 + i;
        float4 vv;
        vv.x = acc[i][0]; vv.y = acc[i][1]; vv.z = acc[i][2]; vv.w = acc[i][3];
        *(float4*)(part + (((size_t)b * 8 + ks) * R_ + r) * C_ + ct * 64 + tcol * 4) = vv;
    }
}

__global__ __launch_bounds__(256) void pkv_reduce_kernel(const float* __restrict__ part,
                                                         unsigned short* __restrict__ pkvx) {
    const size_t idx = (size_t)blockIdx.x * 256 + threadIdx.x;
    const size_t b = idx / ((size_t)R_ * C_);
    const size_t rem = idx % ((size_t)R_ * C_);
    float s = 0.f;
    #pragma unroll
    for (int ks = 0; ks < 8; ++ks) s += part[(b * 8 + ks) * ((size_t)R_ * C_) + rem];
    pkvx[idx] = f2bf(s);
}

// ---------------- attention-2 fused, MFMA ----------------
__global__ __launch_bounds__(256) void attn2_kernel(const unsigned short* __restrict__ q,
                                                    const unsigned short* __restrict__ k,
                                                    const unsigned short* __restrict__ vT,
                                                    const unsigned short* __restrict__ gate,
                                                    unsigned short* __restrict__ hb) {
    const int b = blockIdx.y, l0 = blockIdx.x * 32;
    const int tid = threadIdx.x, w = tid >> 6, lane = tid & 63;
    __shared__ float sc_s[32][68];
    __shared__ unsigned short al_s[32][72];

    {
        f32x4v acc[2];
        acc[0] = f32x4v{0.f,0.f,0.f,0.f}; acc[1] = f32x4v{0.f,0.f,0.f,0.f};
        const int r0 = w * 16;
        #pragma unroll
        for (int kk = 0; kk < 2; ++kk) {
            const bf16x8 bfr = *(const bf16x8*)(k + ((size_t)b * 64 + r0 + (lane & 15)) * 64 + kk * 32 + (lane >> 4) * 8);
            #pragma unroll
            for (int m = 0; m < 2; ++m) {
                const bf16x8 af = *(const bf16x8*)(q + ((size_t)b * L_ + l0 + m * 16 + (lane & 15)) * 64 + kk * 32 + (lane >> 4) * 8);
                acc[m] = __builtin_amdgcn_mfma_f32_16x16x32_bf16(af, bfr, acc[m], 0, 0, 0);
            }
        }
        #pragma unroll
        for (int m = 0; m < 2; ++m)
            #pragma unroll
            for (int i = 0; i < 4; ++i)
                sc_s[m * 16 + (lane >> 4) * 4 + i][r0 + (lane & 15)] = acc[m][i];
    }
    __syncthreads();
    {
        const int t = tid >> 3, rg = tid & 7;
        float v[8];
        float mx = -3.4e38f;
        #pragma unroll
        for (int j = 0; j < 8; ++j) { v[j] = sc_s[t][rg * 8 + j] * 0.125f; mx = fmaxf(mx, v[j]); }
        #pragma unroll
        for (int o = 1; o < 8; o <<= 1) mx = fmaxf(mx, __shfl_xor(mx, o));
        float es = 0.f;
        #pragma unroll
        for (int j = 0; j < 8; ++j) { v[j] = expf(v[j] - mx); es += v[j]; }
        #pragma unroll
        for (int o = 1; o < 8; o <<= 1) es += __shfl_xor(es, o);
        const float inv = 1.0f / es;
        #pragma unroll
        for (int j = 0; j < 8; ++j) al_s[t][rg * 8 + j] = f2bf(v[j] * inv);
    }
    __syncthreads();
    bf16x8 bl[2][2];
    #pragma unroll
    for (int n = 0; n < 2; ++n)
        #pragma unroll
        for (int kk = 0; kk < 2; ++kk)
            bl[n][kk] = *(const bf16x8*)&al_s[n * 16 + (lane & 15)][kk * 32 + (lane >> 4) * 8];
    const int hbase = w * 256;
    #pragma unroll 4
    for (int mi = 0; mi < 16; ++mi) {
        const int h0 = hbase + mi * 16;
        const unsigned short* ap = vT + ((size_t)b * H_ + h0 + (lane & 15)) * 64 + (lane >> 4) * 8;
        const bf16x8 a0 = *(const bf16x8*)(ap);
        const bf16x8 a1 = *(const bf16x8*)(ap + 32);
        f32x4v acc[2];
        acc[0] = f32x4v{0.f,0.f,0.f,0.f}; acc[1] = f32x4v{0.f,0.f,0.f,0.f};
        #pragma unroll
        for (int n = 0; n < 2; ++n) {
            acc[n] = __builtin_amdgcn_mfma_f32_16x16x32_bf16(a0, bl[n][0], acc[n], 0, 0, 0);
            acc[n] = __builtin_amdgcn_mfma_f32_16x16x32_bf16(a1, bl[n][1], acc[n], 0, 0, 0);
        }
        #pragma unroll
        for (int n = 0; n < 2; ++n) {
            const size_t base = ((size_t)b * L_ + l0 + n * 16 + (lane & 15)) * H_ + h0 + (lane >> 4) * 4;
            const ushort4 g = *(const ushort4*)(gate + base);
            ushort4 o;
            o.x = f2bf(bf2f(g.x) * acc[n][0]);
            o.y = f2bf(bf2f(g.y) * acc[n][1]);
            o.z = f2bf(bf2f(g.z) * acc[n][2]);
            o.w = f2bf(bf2f(g.w) * acc[n][3]);
            *(ushort4*)(hb + base) = o;
        }
    }
}

// ---------------- launch ----------------
extern "C" void kernel_launch(void* const* d_in, const int* in_sizes, int n_in,
                              void* d_out, int out_size, void* d_ws, size_t ws_size,
                              hipStream_t stream) {
    const float* qx   = (const float*)d_in[0];
    const float* vx   = (const float*)d_in[1];
    const int*   maskPAD2 = (const int*)d_in[2];
    const float* WQ1  = (const float*)d_in[3];
    const float* WK1  = (const float*)d_in[4];
    const float* WV1  = (const float*)d_in[5];
    const float* WO1  = (const float*)d_in[6];
    const float* qln_g = (const float*)d_in[7];
    const float* qln_b = (const float*)d_in[8];
    const float* Wp   = (const float*)d_in[9];
    const float* bp   = (const float*)d_in[10];
    const float* Wq2  = (const float*)d_in[11];
    const float* bq2  = (const float*)d_in[12];
    const float* Wk2  = (const float*)d_in[13];
    const float* bk2  = (const float*)d_in[14];
    const float* Wv2  = (const float*)d_in[15];
    const float* bv2  = (const float*)d_in[16];
    const float* Wu   = (const float*)d_in[17];
    const float* bu   = (const float*)d_in[18];
    const float* Wo2  = (const float*)d_in[19];
    const float* bo2  = (const float*)d_in[20];
    const float* ln_g = (const float*)d_in[21];
    const float* ln_b = (const float*)d_in[22];
    float* out = (float*)d_out;

    // ---- workspace layout ----
    char* p = (char*)d_ws;
    const size_t NC2 = (size_t)N_ * C_ * 2;          // 16.78 MB
    unsigned short* qx_bf = (unsigned short*)p; p += NC2;         // -> zin_bf -> h_bf[0:half]
    unsigned short* Q_bf  = (unsigned short*)p; p += NC2;         // -> h_bf[half:]
    unsigned short* KV_bf = (unsigned short*)p; p += 2 * NC2;     // -> gate
    unsigned short* vc_bf = (unsigned short*)p; p += NC2;         // -> qx1_bf
    float* t1    = (float*)p; p += (size_t)N_ * C_ * 4;           // -> t2
    float* qx1f  = (float*)p; p += (size_t)N_ * C_ * 4;
    unsigned short* vx_bf = (unsigned short*)p; p += NC2;
    float* pscore  = (float*)p; p += (size_t)N_ * R_ * 4;
    float* pAlpha  = (float*)p; p += (size_t)N_ * R_ * 4;
    unsigned short* queries = (unsigned short*)p; p += (size_t)N_ * DK_ * 2;
    unsigned short* keysB   = (unsigned short*)p; p += (size_t)B_ * R_ * DK_ * 2;
    unsigned short* valT    = (unsigned short*)p; p += (size_t)B_ * H_ * R_ * 2;
    unsigned short* pkvx_bf = (unsigned short*)p; p += (size_t)B_ * R_ * C_ * 2;
    float* part    = (float*)p; p += (size_t)B_ * 8 * R_ * C_ * 4;
    float* segsum  = (float*)p; p += (size_t)B_ * NSEG * C_ * 4;
    unsigned short* wq1t  = (unsigned short*)p; p += (size_t)512 * C_ * 2;
    unsigned short* wkv1t = (unsigned short*)p; p += (size_t)1024 * C_ * 2;
    unsigned short* wo1t  = (unsigned short*)p; p += (size_t)C_ * 512 * 2;
    unsigned short* wpt   = (unsigned short*)p; p += (size_t)R_ * C_ * 2;
    unsigned short* wq2t  = (unsigned short*)p; p += (size_t)DK_ * C_ * 2;
    unsigned short* wk2t  = (unsigned short*)p; p += (size_t)DK_ * C_ * 2;
    unsigned short* wv2t  = (unsigned short*)p; p += (size_t)H_ * C_ * 2;
    unsigned short* wut   = (unsigned short*)p; p += (size_t)H_ * C_ * 2;
    unsigned short* wo2t  = (unsigned short*)p; p += (size_t)C_ * H_ * 2;

    unsigned short* zin_bf = qx_bf;       // qx_bf dead after Q gemm
    unsigned short* h_bf   = qx_bf;       // spans qx_bf + Q_bf
    unsigned short* gate   = KV_bf;       // KV dead after attn1
    unsigned short* qx1_bf = vc_bf;       // vc dead after KV gemm
    float* t2 = t1;

    // 1) qx prep (cvt + segsum fused), vx cvt, weight prep
    qxprep_kernel<<<dim3(NSEG, B_), 512, 0, stream>>>(qx, qx_bf, segsum);
    cvt_kernel<<<(N_ * C_) / (256 * 8), 256, 0, stream>>>(vx, vx_bf);
    WtArgs wa;
    wa.d[0] = {WQ1, wq1t, 512, 512};
    wa.d[1] = {WK1, wkv1t, 512, 512};
    wa.d[2] = {WV1, wkv1t + (size_t)512 * 512, 512, 512};
    wa.d[3] = {WO1, wo1t, 512, 512};
    wa.d[4] = {Wp,  wpt,  512, 64};
    wa.d[5] = {Wq2, wq2t, 512, 64};
    wa.d[6] = {Wk2, wk2t, 512, 64};
    wa.d[7] = {Wv2, wv2t, 512, 1024};
    wa.d[8] = {Wu,  wut,  512, 1024};
    wa.d[9] = {Wo2, wo2t, 1024, 512};
    wtrans_all_kernel<<<dim3(32, 32, 10), dim3(32, 8), 0, stream>>>(wa);
    // 2) running mean (bf16)
    seg_scan_kernel<<<dim3(NSEG, B_), 512, 0, stream>>>(qx_bf, segsum, vc_bf);
    // 3) merged Q + KV projections
    gemm_qkv<<<dim3(N_ / 128, 12), 256, 0, stream>>>(qx_bf, wq1t, Q_bf, vc_bf, wkv1t, KV_bf);
    // 4) attn1 -> zin (bf16, overwrites qx_bf)
    attn1_kernel<<<N_ / 4, 256, 0, stream>>>(Q_bf, KV_bf, zin_bf);
    // 5) WO1 -> t1 f32
    gemm_bf16<128, 0, false, 0><<<dim3(N_ / 128, 4), 256, 0, stream>>>(zin_bf, wo1t, nullptr, t1, 512, 512);
    // 6) qx1 = LN(qx + t1)
    ln_kernel<<<N_ / 4, 256, 0, stream>>>(qx, t1, qln_g, qln_b, qx1f, qx1_bf);
    // 7) gate = silu(qx1 @ Wu + bu)
    gemm_bf16<128, 1, true, 1><<<dim3(N_ / 128, 8), 256, 0, stream>>>(qx1_bf, wut, bu, gate, 512, 1024);
    // 8) pseudo-attn
    gemm_bf16<64, 0, true, 0><<<dim3(N_ / 128, 1), 256, 0, stream>>>(vx_bf, wpt, bp, pscore, 512, 64);
    psoftmax_kernel<<<dim3(R_, B_), 256, 0, stream>>>(pscore, maskPAD2, pAlpha);
    pkv_partial_kernel<<<dim3(8, 8, B_), 256, 0, stream>>>(pAlpha, vx_bf, part);
    pkv_reduce_kernel<<<(B_ * R_ * C_) / 256, 256, 0, stream>>>(part, pkvx_bf);
    // 9) queries; merged keys2 + values2(valT)
    gemm_bf16<64, 1, true, 1><<<dim3(N_ / 128, 1), 256, 0, stream>>>(qx1_bf, wq2t, bq2, queries, 512, 64);
    gemm_kv2<<<dim3((B_ * R_) / 128, 17), 256, 0, stream>>>(pkvx_bf, wk2t, bk2, keysB, wv2t, bv2, valT);
    // 10) fused attn2 -> h bf16
    attn2_kernel<<<dim3(L_ / 32, B_), 256, 0, stream>>>(queries, keysB, valT, gate, h_bf);
    // 11) t2 = h @ Wo2 + bo2 ; out = LN(qx1 + t2)
    gemm_bf16<128, 0, true, 0><<<dim3(N_ / 128, 4), 256, 0, stream>>>(h_bf, wo2t, bo2, t2, 1024, 512);
    ln_kernel<<<N_ / 4, 256, 0, stream>>>(qx1f, t2, ln_g, ln_b, out, nullptr);
}

// Round 10
// 446.976 us; speedup vs baseline: 3.1377x; 1.0010x over previous
//
#include <hip/hip_runtime.h>
#include <hip/hip_bf16.h>

#define B_ 8
#define L_ 2048
#define C_ 512
#define DK_ 64
#define M_ 8
#define R_ 64
#define H_ 1024
#define N_ (B_*L_)
#define NEG_ (-32767.0f)
#define NSEG 32
#define SEGLEN 64

typedef short bf16x8 __attribute__((ext_vector_type(8)));
typedef unsigned short us8 __attribute__((ext_vector_type(8)));
typedef float f32x4v __attribute__((ext_vector_type(4)));

__device__ __forceinline__ float siluf_(float x) { return x / (1.0f + expf(-x)); }

__device__ __forceinline__ unsigned short f2bf(float f) {
    __hip_bfloat16 h = __float2bfloat16(f);
    return __builtin_bit_cast(unsigned short, h);
}
__device__ __forceinline__ float bf2f(unsigned short u) {
    unsigned v = (unsigned)u << 16;
    return __builtin_bit_cast(float, v);
}

// async global->LDS, 16B per lane; LDS dest = wave base + lane*16 (linear)
__device__ __forceinline__ void gload_lds16(const void* g, void* l) {
    __builtin_amdgcn_global_load_lds(
        (const __attribute__((address_space(1))) unsigned int*)(uintptr_t)g,
        (__attribute__((address_space(3))) unsigned int*)(unsigned)(uintptr_t)l,
        16, 0, 0);
}

// ---------------- qx prep: fp32 -> bf16 + per-segment sums (merged cvt+seg_sum) ----------------
__global__ __launch_bounds__(512) void qxprep_kernel(const float* __restrict__ qx,
                                                     unsigned short* __restrict__ qx_bf,
                                                     float* __restrict__ segsum) {
    const int seg = blockIdx.x, b = blockIdx.y, c = threadIdx.x;
    const size_t base = ((size_t)b * L_ + (size_t)seg * SEGLEN) * C_ + c;
    const float* p = qx + base;
    unsigned short* o = qx_bf + base;
    float s = 0.f;
    #pragma unroll 8
    for (int i = 0; i < SEGLEN; ++i) {
        const float v = p[(size_t)i * C_];
        s += v;
        o[(size_t)i * C_] = f2bf(v);
    }
    segsum[((size_t)b * NSEG + seg) * C_ + c] = s;
}

// ---------------- fp32 -> bf16 (vx only) ----------------
__global__ __launch_bounds__(256) void cvt_kernel(const float* __restrict__ s,
                                                  unsigned short* __restrict__ d) {
    const size_t i = ((size_t)blockIdx.x * 256 + threadIdx.x) * 8;
    const float4 v0 = *(const float4*)(s + i);
    const float4 v1 = *(const float4*)(s + i + 4);
    us8 o;
    o[0] = f2bf(v0.x); o[1] = f2bf(v0.y); o[2] = f2bf(v0.z); o[3] = f2bf(v0.w);
    o[4] = f2bf(v1.x); o[5] = f2bf(v1.y); o[6] = f2bf(v1.z); o[7] = f2bf(v1.w);
    *(us8*)(d + i) = o;
}

// ---------------- batched weight transpose+convert: W[K][N] f32 -> Wt[N][K] bf16 ----------------
struct WtDesc { const float* src; unsigned short* dst; int K; int N; };
struct WtArgs { WtDesc d[10]; };

__global__ __launch_bounds__(256) void wtrans_all_kernel(WtArgs a) {
    const WtDesc w = a.d[blockIdx.z];
    const int n0 = blockIdx.x * 32, k0 = blockIdx.y * 32;
    if (n0 >= w.N || k0 >= w.K) return;
    __shared__ float t[32][33];
    const int tx = threadIdx.x, ty = threadIdx.y;
    #pragma unroll
    for (int i = 0; i < 32; i += 8)
        t[ty + i][tx] = w.src[(size_t)(k0 + ty + i) * w.N + n0 + tx];
    __syncthreads();
    #pragma unroll
    for (int i = 0; i < 32; i += 8)
        w.dst[(size_t)(n0 + ty + i) * w.K + k0 + tx] = f2bf(t[tx][ty + i]);
}

// ---------------- segmented scan (running mean), bf16 in/out ----------------
__global__ __launch_bounds__(512) void seg_scan_kernel(const unsigned short* __restrict__ qx,
                                                       const float* __restrict__ segsum,
                                                       unsigned short* __restrict__ vc) {
    const int seg = blockIdx.x, b = blockIdx.y, c = threadIdx.x;
    float off = 0.f;
    for (int s = 0; s < seg; ++s) off += segsum[((size_t)b * NSEG + s) * C_ + c];
    const unsigned short* p = qx + ((size_t)b * L_ + (size_t)seg * SEGLEN) * C_ + c;
    unsigned short* o = vc + ((size_t)b * L_ + (size_t)seg * SEGLEN) * C_ + c;
    float run = off;
    for (int i = 0; i < SEGLEN; ++i) {
        run += bf2f(p[(size_t)i * C_]);
        const int l = seg * SEGLEN + i;
        o[(size_t)i * C_] = f2bf(run / (float)(l + 1));
    }
}

// ---------------- bf16 MFMA GEMM body (m97 structure + LDS-staged epilogue) ----------------
// A[M][K] bf16, Wt[N][K] bf16. OUT: 0 = f32 row-major (2-pass f32 stage),
// 1 = bf16 row-major (us8 stage), 2 = bf16 transposed-by-64 valT (BN=64 only).
template<int BN, int ACT, bool BIAS, int OUT>
__device__ __forceinline__ void gemm_body(char* smem,
        const unsigned short* __restrict__ A, const unsigned short* __restrict__ Wt,
        const float* __restrict__ bias, void* __restrict__ Cout,
        int K, int N, int m0, int n0, int tid) {
    constexpr int BK = 64;
    constexpr int WN = BN / 2;
    constexpr int TN = WN / 16;
    unsigned short* Alds = (unsigned short*)smem;             // 128*64 us = 16KB
    unsigned short* Blds = (unsigned short*)(smem + 16384);   // BN*64 us
    const int w = tid >> 6, lane = tid & 63;
    const int wm = w >> 1, wn = w & 1;

    f32x4v acc[4][TN];
    #pragma unroll
    for (int m = 0; m < 4; ++m)
        #pragma unroll
        for (int n = 0; n < TN; ++n)
            acc[m][n] = f32x4v{0.f, 0.f, 0.f, 0.f};

    const int lrow = lane >> 3;
    const int lk = (lane & 7) * 8;

    for (int k0 = 0; k0 < K; k0 += BK) {
        __syncthreads();
        #pragma unroll
        for (int i = 0; i < 4; ++i) {
            const int c = w * 4 + i;
            const int row = c * 8 + lrow;
            gload_lds16(A + (size_t)(m0 + row) * K + k0 + lk, (char*)Alds + c * 1024);
        }
        #pragma unroll
        for (int i = 0; i < BN / 32; ++i) {
            const int c = w * (BN / 32) + i;
            const int col = c * 8 + lrow;
            gload_lds16(Wt + (size_t)(n0 + col) * K + k0 + lk, (char*)Blds + c * 1024);
        }
        __syncthreads();
        #pragma unroll
        for (int kk = 0; kk < 2; ++kk) {
            const int ko = kk * 64 + (lane >> 4) * 16;
            bf16x8 af[4], bfr[TN];
            #pragma unroll
            for (int m = 0; m < 4; ++m)
                af[m] = *(const bf16x8*)((const char*)Alds + (wm * 64 + m * 16 + (lane & 15)) * 128 + ko);
            #pragma unroll
            for (int n = 0; n < TN; ++n)
                bfr[n] = *(const bf16x8*)((const char*)Blds + (wn * WN + n * 16 + (lane & 15)) * 128 + ko);
            #pragma unroll
            for (int m = 0; m < 4; ++m)
                #pragma unroll
                for (int n = 0; n < TN; ++n)
                    acc[m][n] = __builtin_amdgcn_mfma_f32_16x16x32_bf16(af[m], bfr[n], acc[m][n], 0, 0, 0);
        }
    }

    // bias per n-frag (col fixed per lane)
    const int r0 = (lane >> 4) * 4;
    float bv[TN];
    #pragma unroll
    for (int n = 0; n < TN; ++n)
        bv[n] = BIAS ? bias[n0 + wn * WN + n * 16 + (lane & 15)] : 0.f;

    if constexpr (OUT == 1) {
        __syncthreads();                                  // all MFMA LDS reads done
        unsigned short* stg = (unsigned short*)smem;      // [128][BN]
        #pragma unroll
        for (int n = 0; n < TN; ++n) {
            const int cl = wn * WN + n * 16 + (lane & 15);
            #pragma unroll
            for (int m = 0; m < 4; ++m)
                #pragma unroll
                for (int r = 0; r < 4; ++r) {
                    float val = acc[m][n][r] + bv[n];
                    if constexpr (ACT == 1) val = siluf_(val);
                    stg[(wm * 64 + m * 16 + r0 + r) * BN + cl] = f2bf(val);
                }
        }
        __syncthreads();
        constexpr int CH = 128 * BN / 8 / 256;
        #pragma unroll
        for (int i = 0; i < CH; ++i) {
            const int idx = i * 256 + tid;
            const int row = (idx * 8) / BN, col = (idx * 8) % BN;
            *(us8*)((unsigned short*)Cout + (size_t)(m0 + row) * N + n0 + col) = *(const us8*)&stg[idx * 8];
        }
    } else if constexpr (OUT == 2) {
        // BN==64 only. stage [2*BN][72] us (pad 8 for alignment+banks)
        __syncthreads();
        unsigned short* stg = (unsigned short*)smem;
        #pragma unroll
        for (int n = 0; n < TN; ++n) {
            const int cl = wn * WN + n * 16 + (lane & 15);
            #pragma unroll
            for (int m = 0; m < 4; ++m)
                #pragma unroll
                for (int r = 0; r < 4; ++r) {
                    float val = acc[m][n][r] + bv[n];
                    if constexpr (ACT == 1) val = siluf_(val);
                    stg[(wm * BN + cl) * 72 + m * 16 + r0 + r] = f2bf(val);
                }
        }
        __syncthreads();
        constexpr int CH = 2 * BN * 64 / 8 / 256;
        #pragma unroll
        for (int i = 0; i < CH; ++i) {
            const int idx = i * 256 + tid;
            const int vrow = idx >> 3, j = (idx & 7) * 8;
            const int h = vrow >= BN ? 1 : 0;
            const int col = vrow & (BN - 1);
            *(us8*)((unsigned short*)Cout + (((size_t)(m0 >> 6) + h) * N + n0 + col) * 64 + j)
                = *(const us8*)&stg[vrow * 72 + j];
        }
    } else {
        // OUT==0: f32 row-major, two 64-row passes through a [64][BN] f32 stage
        float* stgf = (float*)smem;
        #pragma unroll
        for (int pass = 0; pass < 2; ++pass) {
            __syncthreads();
            if (wm == pass) {
                #pragma unroll
                for (int n = 0; n < TN; ++n) {
                    const int cl = wn * WN + n * 16 + (lane & 15);
                    #pragma unroll
                    for (int m = 0; m < 4; ++m)
                        #pragma unroll
                        for (int r = 0; r < 4; ++r) {
                            float val = acc[m][n][r] + bv[n];
                            if constexpr (ACT == 1) val = siluf_(val);
                            stgf[(m * 16 + r0 + r) * BN + cl] = val;
                        }
                }
            }
            __syncthreads();
            constexpr int CH = 64 * BN / 4 / 256;
            #pragma unroll
            for (int i = 0; i < CH; ++i) {
                const int idx = i * 256 + tid;
                const int row = (idx * 4) / BN, col = (idx * 4) % BN;
                *(float4*)((float*)Cout + (size_t)(m0 + pass * 64 + row) * N + n0 + col)
                    = *(const float4*)&stgf[idx * 4];
            }
        }
    }
}

template<int BN, int ACT, bool BIAS, int OUT>
__global__ __launch_bounds__(256) void gemm_bf16(const unsigned short* __restrict__ A,
                                                 const unsigned short* __restrict__ Wt,
                                                 const float* __restrict__ bias,
                                                 void* __restrict__ Cout,
                                                 int K, int N) {
    __shared__ char smem[BN == 128 ? 32768 : 24576];
    gemm_body<BN, ACT, BIAS, OUT>(smem, A, Wt, bias, Cout, K, N,
                                  blockIdx.x * 128, blockIdx.y * BN, threadIdx.x);
}

// merged Q (y<4) + KV (y>=4) projections, both from K=512, bf16 out
__global__ __launch_bounds__(256) void gemm_qkv(const unsigned short* __restrict__ qxA,
                                                const unsigned short* __restrict__ wq,
                                                unsigned short* __restrict__ Qo,
                                                const unsigned short* __restrict__ vcA,
                                                const unsigned short* __restrict__ wkv,
                                                unsigned short* __restrict__ KVo) {
    __shared__ char smem[32768];
    if (blockIdx.y < 4)
        gemm_body<128, 0, false, 1>(smem, qxA, wq, nullptr, Qo, 512, 512,
                                    blockIdx.x * 128, blockIdx.y * 128, threadIdx.x);
    else
        gemm_body<128, 0, false, 1>(smem, vcA, wkv, nullptr, KVo, 512, 1024,
                                    blockIdx.x * 128, (blockIdx.y - 4) * 128, threadIdx.x);
}

// merged keys2 (y==0, bf16) + values2 (y>=1, transposed valT) from pkvx, M=512
__global__ __launch_bounds__(256) void gemm_kv2(const unsigned short* __restrict__ pkvx,
                                                const unsigned short* __restrict__ wk2,
                                                const float* __restrict__ bk2,
                                                unsigned short* __restrict__ keys,
                                                const unsigned short* __restrict__ wv2,
                                                const float* __restrict__ bv2,
                                                unsigned short* __restrict__ valT) {
    __shared__ char smem[24576];
    if (blockIdx.y == 0)
        gemm_body<64, 1, true, 1>(smem, pkvx, wk2, bk2, keys, 512, 64,
                                  blockIdx.x * 128, 0, threadIdx.x);
    else
        gemm_body<64, 1, true, 2>(smem, pkvx, wv2, bv2, valT, 512, 1024,
                                  blockIdx.x * 128, (blockIdx.y - 1) * 64, threadIdx.x);
}

// ---------------- attention-1: one wave per row, us8 vectorized, head = lane>>3 ----------------
__global__ __launch_bounds__(256) void attn1_kernel(const unsigned short* __restrict__ Q,
                                                    const unsigned short* __restrict__ KV,
                                                    unsigned short* __restrict__ zbf) {
    const int w = threadIdx.x >> 6, lane = threadIdx.x & 63;
    const size_t row = (size_t)blockIdx.x * 4 + w;
    const int l = (int)(row & (L_ - 1));
    unsigned short* zr = zbf + row * 512 + lane * 8;
    if (l == 0) {
        us8 z;
        #pragma unroll
        for (int j = 0; j < 8; ++j) z[j] = 0;
        *(us8*)zr = z;
        return;
    }
    const us8 q8 = *(const us8*)(Q + row * 512 + lane * 8);
    const us8 k8 = *(const us8*)(KV + (row - 1) * 1024 + lane * 8);
    float p = 0.f;
    #pragma unroll
    for (int j = 0; j < 8; ++j) p += bf2f(q8[j]) * bf2f(k8[j]);
    p += __shfl_xor(p, 1); p += __shfl_xor(p, 2); p += __shfl_xor(p, 4);
    const float sig = 1.0f / (1.0f + expf(-p * 0.125f));
    const us8 v8 = *(const us8*)(KV + (row - 1) * 1024 + 512 + lane * 8);
    us8 o;
    #pragma unroll
    for (int j = 0; j < 8; ++j) o[j] = f2bf(sig * bf2f(v8[j]));
    *(us8*)zr = o;
}

// ---------------- fused residual + LayerNorm ----------------
// X: f32 (XBF=0) or bf16 (XBF=1); Y: bf16. out (f32) and outb (bf16) optional.
template<int XBF>
__global__ __launch_bounds__(256) void ln_kernel(const void* __restrict__ Xp,
                                                 const unsigned short* __restrict__ Y,
                                                 const float* __restrict__ g,
                                                 const float* __restrict__ beta,
                                                 float* __restrict__ out,
                                                 unsigned short* __restrict__ outb) {
    const int w = threadIdx.x >> 6, lane = threadIdx.x & 63;
    const size_t row = (size_t)blockIdx.x * 4 + w;
    float v[8];
    if constexpr (XBF == 0) {
        const float4* x4 = (const float4*)((const float*)Xp + row * C_);
        const float4 a = x4[lane * 2 + 0], b2 = x4[lane * 2 + 1];
        v[0] = a.x; v[1] = a.y; v[2] = a.z; v[3] = a.w;
        v[4] = b2.x; v[5] = b2.y; v[6] = b2.z; v[7] = b2.w;
    } else {
        const us8 x8 = *(const us8*)((const unsigned short*)Xp + row * C_ + lane * 8);
        #pragma unroll
        for (int j = 0; j < 8; ++j) v[j] = bf2f(x8[j]);
    }
    const us8 y8 = *(const us8*)(Y + row * C_ + lane * 8);
    #pragma unroll
    for (int j = 0; j < 8; ++j) v[j] += bf2f(y8[j]);
    float s = 0.f;
    #pragma unroll
    for (int j = 0; j < 8; ++j) s += v[j];
    #pragma unroll
    for (int o = 32; o; o >>= 1) s += __shfl_xor(s, o);
    const float mean = s * (1.0f / 512.0f);
    float q = 0.f;
    #pragma unroll
    for (int j = 0; j < 8; ++j) { const float t = v[j] - mean; q += t * t; }
    #pragma unroll
    for (int o = 32; o; o >>= 1) q += __shfl_xor(q, o);
    const float rstd = rsqrtf(q * (1.0f / 512.0f) + 1e-5f);
    const float4 g0 = ((const float4*)g)[lane * 2], g1 = ((const float4*)g)[lane * 2 + 1];
    const float4 bb0 = ((const float4*)beta)[lane * 2], bb1 = ((const float4*)beta)[lane * 2 + 1];
    float o8[8];
    o8[0] = (v[0] - mean) * rstd * g0.x + bb0.x;
    o8[1] = (v[1] - mean) * rstd * g0.y + bb0.y;
    o8[2] = (v[2] - mean) * rstd * g0.z + bb0.z;
    o8[3] = (v[3] - mean) * rstd * g0.w + bb0.w;
    o8[4] = (v[4] - mean) * rstd * g1.x + bb1.x;
    o8[5] = (v[5] - mean) * rstd * g1.y + bb1.y;
    o8[6] = (v[6] - mean) * rstd * g1.z + bb1.z;
    o8[7] = (v[7] - mean) * rstd * g1.w + bb1.w;
    if (out) {
        float4 o0, o1;
        o0.x = o8[0]; o0.y = o8[1]; o0.z = o8[2]; o0.w = o8[3];
        o1.x = o8[4]; o1.y = o8[5]; o1.z = o8[6]; o1.w = o8[7];
        ((float4*)(out + row * C_))[lane * 2 + 0] = o0;
        ((float4*)(out + row * C_))[lane * 2 + 1] = o1;
    }
    if (outb) {
        us8 pk;
        #pragma unroll
        for (int j = 0; j < 8; ++j) pk[j] = f2bf(o8[j]);
        *(us8*)(outb + row * C_ + lane * 8) = pk;
    }
}

// ---------------- masked softmax over L per (b,r) ----------------
__global__ __launch_bounds__(256) void psoftmax_kernel(const float* __restrict__ pscore,
                                                       const int* __restrict__ mask,
                                                       float* __restrict__ pAlpha) {
    const int r = blockIdx.x, b = blockIdx.y, t = threadIdx.x;
    __shared__ float red[256];
    float sv[8];
    float lm = -3.4e38f;
    #pragma unroll
    for (int i = 0; i < 8; ++i) {
        const int l = t + i * 256;
        float x = pscore[((size_t)b * L_ + l) * R_ + r];
        if (mask[(size_t)b * L_ + l] == 0) x = NEG_;
        sv[i] = x; lm = fmaxf(lm, x);
    }
    red[t] = lm; __syncthreads();
    for (int o = 128; o; o >>= 1) { if (t < o) red[t] = fmaxf(red[t], red[t + o]); __syncthreads(); }
    const float mx = red[0]; __syncthreads();
    float ls = 0.f;
    #pragma unroll
    for (int i = 0; i < 8; ++i) { sv[i] = expf(sv[i] - mx); ls += sv[i]; }
    red[t] = ls; __syncthreads();
    for (int o = 128; o; o >>= 1) { if (t < o) red[t] += red[t + o]; __syncthreads(); }
    const float inv = 1.0f / red[0];
    #pragma unroll
    for (int i = 0; i < 8; ++i)
        pAlpha[((size_t)b * L_ + t + i * 256) * R_ + r] = sv[i] * inv;
}

// ---------------- pkvx = pAlpha^T @ vx (bf16), K-split partials ----------------
__global__ __launch_bounds__(256) void pkv_partial_kernel(const float* __restrict__ pAlpha,
                                                          const unsigned short* __restrict__ vx,
                                                          float* __restrict__ part) {
    const int ct = blockIdx.x, ks = blockIdx.y, b = blockIdx.z;
    constexpr int KT = 16;
    __shared__ float Pa[KT][64 + 4];
    __shared__ float Vx[KT][64 + 4];
    const int tid = threadIdx.x;
    const int trow = tid >> 4, tcol = tid & 15;
    float acc[4][4];
    #pragma unroll
    for (int i = 0; i < 4; ++i)
        #pragma unroll
        for (int j = 0; j < 4; ++j) acc[i][j] = 0.f;
    const int l0 = ks * 256;
    for (int kk = 0; kk < 256; kk += KT) {
        const int lrow = tid >> 4;
        const int q4 = (tid & 15) << 2;
        const size_t lidx = (size_t)b * L_ + l0 + kk + lrow;
        *(float4*)&Pa[lrow][q4] = *(const float4*)(pAlpha + lidx * R_ + q4);
        const ushort4 vv4 = *(const ushort4*)(vx + lidx * C_ + ct * 64 + q4);
        Vx[lrow][q4 + 0] = bf2f(vv4.x);
        Vx[lrow][q4 + 1] = bf2f(vv4.y);
        Vx[lrow][q4 + 2] = bf2f(vv4.z);
        Vx[lrow][q4 + 3] = bf2f(vv4.w);
        __syncthreads();
        #pragma unroll
        for (int k = 0; k < KT; ++k) {
            float a[4], v[4];
            *(float4*)&a[0] = *(const float4*)&Pa[k][trow * 4];
            *(float4*)&v[0] = *(const float4*)&Vx[k][tcol * 4];
            #pragma unroll
            for (int i = 0; i < 4; ++i)
                #pragma unroll
                for (int j = 0; j < 4; ++j)
                    acc[i][j] = fmaf(a[i], v[j], acc[i][j]);
        }
        __syncthreads();
    }
    #pragma unroll
    for (int i = 0; i < 4; ++i) {
        const int r = trow * 4 + i;
        float4 vv;
        vv.x = acc[i][0]; vv.y = acc[i][1]; vv.z = acc[i][2]; vv.w = acc[i][3];
        *(float4*)(part + (((size_t)b * 8 + ks) * R_ + r) * C_ + ct * 64 + tcol * 4) = vv;
    }
}

__global__ __launch_bounds__(256) void pkv_reduce_kernel(const float* __restrict__ part,
                                                         unsigned short* __restrict__ pkvx) {
    const size_t idx = (size_t)blockIdx.x * 256 + threadIdx.x;
    const size_t b = idx / ((size_t)R_ * C_);
    const size_t rem = idx % ((size_t)R_ * C_);
    float s = 0.f;
    #pragma unroll
    for (int ks = 0; ks < 8; ++ks) s += part[(b * 8 + ks) * ((size_t)R_ * C_) + rem];
    pkvx[idx] = f2bf(s);
}

// ---------------- attention-2 fused, MFMA ----------------
__global__ __launch_bounds__(256) void attn2_kernel(const unsigned short* __restrict__ q,
                                                    const unsigned short* __restrict__ k,
                                                    const unsigned short* __restrict__ vT,
                                                    const unsigned short* __restrict__ gate,
                                                    unsigned short* __restrict__ hb) {
    const int b = blockIdx.y, l0 = blockIdx.x * 32;
    const int tid = threadIdx.x, w = tid >> 6, lane = tid & 63;
    __shared__ float sc_s[32][68];
    __shared__ unsigned short al_s[32][72];

    {
        f32x4v acc[2];
        acc[0] = f32x4v{0.f,0.f,0.f,0.f}; acc[1] = f32x4v{0.f,0.f,0.f,0.f};
        const int r0 = w * 16;
        #pragma unroll
        for (int kk = 0; kk < 2; ++kk) {
            const bf16x8 bfr = *(const bf16x8*)(k + ((size_t)b * 64 + r0 + (lane & 15)) * 64 + kk * 32 + (lane >> 4) * 8);
            #pragma unroll
            for (int m = 0; m < 2; ++m) {
                const bf16x8 af = *(const bf16x8*)(q + ((size_t)b * L_ + l0 + m * 16 + (lane & 15)) * 64 + kk * 32 + (lane >> 4) * 8);
                acc[m] = __builtin_amdgcn_mfma_f32_16x16x32_bf16(af, bfr, acc[m], 0, 0, 0);
            }
        }
        #pragma unroll
        for (int m = 0; m < 2; ++m)
            #pragma unroll
            for (int i = 0; i < 4; ++i)
                sc_s[m * 16 + (lane >> 4) * 4 + i][r0 + (lane & 15)] = acc[m][i];
    }
    __syncthreads();
    {
        const int t = tid >> 3, rg = tid & 7;
        float v[8];
        float mx = -3.4e38f;
        #pragma unroll
        for (int j = 0; j < 8; ++j) { v[j] = sc_s[t][rg * 8 + j] * 0.125f; mx = fmaxf(mx, v[j]); }
        #pragma unroll
        for (int o = 1; o < 8; o <<= 1) mx = fmaxf(mx, __shfl_xor(mx, o));
        float es = 0.f;
        #pragma unroll
        for (int j = 0; j < 8; ++j) { v[j] = expf(v[j] - mx); es += v[j]; }
        #pragma unroll
        for (int o = 1; o < 8; o <<= 1) es += __shfl_xor(es, o);
        const float inv = 1.0f / es;
        #pragma unroll
        for (int j = 0; j < 8; ++j) al_s[t][rg * 8 + j] = f2bf(v[j] * inv);
    }
    __syncthreads();
    bf16x8 bl[2][2];
    #pragma unroll
    for (int n = 0; n < 2; ++n)
        #pragma unroll
        for (int kk = 0; kk < 2; ++kk)
            bl[n][kk] = *(const bf16x8*)&al_s[n * 16 + (lane & 15)][kk * 32 + (lane >> 4) * 8];
    const int hbase = w * 256;
    #pragma unroll 4
    for (int mi = 0; mi < 16; ++mi) {
        const int h0 = hbase + mi * 16;
        const unsigned short* ap = vT + ((size_t)b * H_ + h0 + (lane & 15)) * 64 + (lane >> 4) * 8;
        const bf16x8 a0 = *(const bf16x8*)(ap);
        const bf16x8 a1 = *(const bf16x8*)(ap + 32);
        f32x4v acc[2];
        acc[0] = f32x4v{0.f,0.f,0.f,0.f}; acc[1] = f32x4v{0.f,0.f,0.f,0.f};
        #pragma unroll
        for (int n = 0; n < 2; ++n) {
            acc[n] = __builtin_amdgcn_mfma_f32_16x16x32_bf16(a0, bl[n][0], acc[n], 0, 0, 0);
            acc[n] = __builtin_amdgcn_mfma_f32_16x16x32_bf16(a1, bl[n][1], acc[n], 0, 0, 0);
        }
        #pragma unroll
        for (int n = 0; n < 2; ++n) {
            const size_t base = ((size_t)b * L_ + l0 + n * 16 + (lane & 15)) * H_ + h0 + (lane >> 4) * 4;
            const ushort4 g = *(const ushort4*)(gate + base);
            ushort4 o;
            o.x = f2bf(bf2f(g.x) * acc[n][0]);
            o.y = f2bf(bf2f(g.y) * acc[n][1]);
            o.z = f2bf(bf2f(g.z) * acc[n][2]);
            o.w = f2bf(bf2f(g.w) * acc[n][3]);
            *(ushort4*)(hb + base) = o;
        }
    }
}

// ---------------- launch ----------------
extern "C" void kernel_launch(void* const* d_in, const int* in_sizes, int n_in,
                              void* d_out, int out_size, void* d_ws, size_t ws_size,
                              hipStream_t stream) {
    const float* qx   = (const float*)d_in[0];
    const float* vx   = (const float*)d_in[1];
    const int*   maskPAD2 = (const int*)d_in[2];
    const float* WQ1  = (const float*)d_in[3];
    const float* WK1  = (const float*)d_in[4];
    const float* WV1  = (const float*)d_in[5];
    const float* WO1  = (const float*)d_in[6];
    const float* qln_g = (const float*)d_in[7];
    const float* qln_b = (const float*)d_in[8];
    const float* Wp   = (const float*)d_in[9];
    const float* bp   = (const float*)d_in[10];
    const float* Wq2  = (const float*)d_in[11];
    const float* bq2  = (const float*)d_in[12];
    const float* Wk2  = (const float*)d_in[13];
    const float* bk2  = (const float*)d_in[14];
    const float* Wv2  = (const float*)d_in[15];
    const float* bv2  = (const float*)d_in[16];
    const float* Wu   = (const float*)d_in[17];
    const float* bu   = (const float*)d_in[18];
    const float* Wo2  = (const float*)d_in[19];
    const float* bo2  = (const float*)d_in[20];
    const float* ln_g = (const float*)d_in[21];
    const float* ln_b = (const float*)d_in[22];
    float* out = (float*)d_out;

    // ---- workspace layout ----
    char* p = (char*)d_ws;
    const size_t NC2 = (size_t)N_ * C_ * 2;          // 16.78 MB
    unsigned short* qx_bf = (unsigned short*)p; p += NC2;         // -> zin_bf -> h_bf[0:half]
    unsigned short* Q_bf  = (unsigned short*)p; p += NC2;         // -> h_bf[half:]
    unsigned short* KV_bf = (unsigned short*)p; p += 2 * NC2;     // -> gate
    unsigned short* vc_bf = (unsigned short*)p; p += NC2;         // -> qx1_bf
    unsigned short* t1    = (unsigned short*)p; p += NC2;         // bf16 now; -> t2
    unsigned short* vx_bf = (unsigned short*)p; p += NC2;
    float* pscore  = (float*)p; p += (size_t)N_ * R_ * 4;
    float* pAlpha  = (float*)p; p += (size_t)N_ * R_ * 4;
    unsigned short* queries = (unsigned short*)p; p += (size_t)N_ * DK_ * 2;
    unsigned short* keysB   = (unsigned short*)p; p += (size_t)B_ * R_ * DK_ * 2;
    unsigned short* valT    = (unsigned short*)p; p += (size_t)B_ * H_ * R_ * 2;
    unsigned short* pkvx_bf = (unsigned short*)p; p += (size_t)B_ * R_ * C_ * 2;
    float* part    = (float*)p; p += (size_t)B_ * 8 * R_ * C_ * 4;
    float* segsum  = (float*)p; p += (size_t)B_ * NSEG * C_ * 4;
    unsigned short* wq1t  = (unsigned short*)p; p += (size_t)512 * C_ * 2;
    unsigned short* wkv1t = (unsigned short*)p; p += (size_t)1024 * C_ * 2;
    unsigned short* wo1t  = (unsigned short*)p; p += (size_t)C_ * 512 * 2;
    unsigned short* wpt   = (unsigned short*)p; p += (size_t)R_ * C_ * 2;
    unsigned short* wq2t  = (unsigned short*)p; p += (size_t)DK_ * C_ * 2;
    unsigned short* wk2t  = (unsigned short*)p; p += (size_t)DK_ * C_ * 2;
    unsigned short* wv2t  = (unsigned short*)p; p += (size_t)H_ * C_ * 2;
    unsigned short* wut   = (unsigned short*)p; p += (size_t)H_ * C_ * 2;
    unsigned short* wo2t  = (unsigned short*)p; p += (size_t)C_ * H_ * 2;

    unsigned short* zin_bf = qx_bf;       // qx_bf dead after Q gemm
    unsigned short* h_bf   = qx_bf;       // spans qx_bf + Q_bf
    unsigned short* gate   = KV_bf;       // KV dead after attn1
    unsigned short* qx1_bf = vc_bf;       // vc dead after KV gemm
    unsigned short* t2 = t1;

    // 1) qx prep (cvt + segsum fused), vx cvt, weight prep
    qxprep_kernel<<<dim3(NSEG, B_), 512, 0, stream>>>(qx, qx_bf, segsum);
    cvt_kernel<<<(N_ * C_) / (256 * 8), 256, 0, stream>>>(vx, vx_bf);
    WtArgs wa;
    wa.d[0] = {WQ1, wq1t, 512, 512};
    wa.d[1] = {WK1, wkv1t, 512, 512};
    wa.d[2] = {WV1, wkv1t + (size_t)512 * 512, 512, 512};
    wa.d[3] = {WO1, wo1t, 512, 512};
    wa.d[4] = {Wp,  wpt,  512, 64};
    wa.d[5] = {Wq2, wq2t, 512, 64};
    wa.d[6] = {Wk2, wk2t, 512, 64};
    wa.d[7] = {Wv2, wv2t, 512, 1024};
    wa.d[8] = {Wu,  wut,  512, 1024};
    wa.d[9] = {Wo2, wo2t, 1024, 512};
    wtrans_all_kernel<<<dim3(32, 32, 10), dim3(32, 8), 0, stream>>>(wa);
    // 2) running mean (bf16)
    seg_scan_kernel<<<dim3(NSEG, B_), 512, 0, stream>>>(qx_bf, segsum, vc_bf);
    // 3) merged Q + KV projections
    gemm_qkv<<<dim3(N_ / 128, 12), 256, 0, stream>>>(qx_bf, wq1t, Q_bf, vc_bf, wkv1t, KV_bf);
    // 4) attn1 -> zin (bf16, overwrites qx_bf)
    attn1_kernel<<<N_ / 4, 256, 0, stream>>>(Q_bf, KV_bf, zin_bf);
    // 5) WO1 -> t1 bf16
    gemm_bf16<128, 0, false, 1><<<dim3(N_ / 128, 4), 256, 0, stream>>>(zin_bf, wo1t, nullptr, t1, 512, 512);
    // 6) qx1 = LN(qx + t1) -> bf16 only
    ln_kernel<0><<<N_ / 4, 256, 0, stream>>>(qx, t1, qln_g, qln_b, nullptr, qx1_bf);
    // 7) gate = silu(qx1 @ Wu + bu)
    gemm_bf16<128, 1, true, 1><<<dim3(N_ / 128, 8), 256, 0, stream>>>(qx1_bf, wut, bu, gate, 512, 1024);
    // 8) pseudo-attn
    gemm_bf16<64, 0, true, 0><<<dim3(N_ / 128, 1), 256, 0, stream>>>(vx_bf, wpt, bp, pscore, 512, 64);
    psoftmax_kernel<<<dim3(R_, B_), 256, 0, stream>>>(pscore, maskPAD2, pAlpha);
    pkv_partial_kernel<<<dim3(8, 8, B_), 256, 0, stream>>>(pAlpha, vx_bf, part);
    pkv_reduce_kernel<<<(B_ * R_ * C_) / 256, 256, 0, stream>>>(part, pkvx_bf);
    // 9) queries; merged keys2 + values2(valT)
    gemm_bf16<64, 1, true, 1><<<dim3(N_ / 128, 1), 256, 0, stream>>>(qx1_bf, wq2t, bq2, queries, 512, 64);
    gemm_kv2<<<dim3((B_ * R_) / 128, 17), 256, 0, stream>>>(pkvx_bf, wk2t, bk2, keysB, wv2t, bv2, valT);
    // 10) fused attn2 -> h bf16
    attn2_kernel<<<dim3(L_ / 32, B_), 256, 0, stream>>>(queries, keysB, valT, gate, h_bf);
    // 11) t2 = h @ Wo2 + bo2 (bf16) ; out = LN(qx1 + t2)
    gemm_bf16<128, 0, true, 1><<<dim3(N_ / 128, 4), 256, 0, stream>>>(h_bf, wo2t, bo2, t2, 1024, 512);
    ln_kernel<1><<<N_ / 4, 256, 0, stream>>>(qx1_bf, t2, ln_g, ln_b, out, nullptr);
}